// Round 3
// baseline (374.913 us; speedup 1.0000x reference)
//
#include <hip/hip_runtime.h>

#define F 64
#define P 32
#define MAXD 10
#define NPB 256      // nodes per bucket (pow2; bucket = dst>>8)
#define NPART 8      // staging partitions ~ XCDs (blockIdx&7)
#define CAP 768      // per (part,bucket) staging capacity (expected ~510, 10+ sigma)
#define OVCAP 16384  // overflow capacity

// ---------------- degree count ----------------
__global__ void k_count_deg(const int* __restrict__ dst, int* __restrict__ deg, int E) {
  int i = blockIdx.x * blockDim.x + threadIdx.x;
  int stride = gridDim.x * blockDim.x;
  for (int e = i; e < E; e += stride) atomicAdd(&deg[dst[e]], 1);
}

// ---------------- hierarchical scan: phase 1 — per-block sums (256 nodes/block) ----------------
__global__ void k_bsum(const int* __restrict__ deg, int* __restrict__ bsum, int N) {
  __shared__ int s[256];
  int t = threadIdx.x;
  int n = blockIdx.x * 256 + t;
  s[t] = (n < N) ? deg[n] : 0;
  __syncthreads();
  for (int o = 128; o > 0; o >>= 1) {
    if (t < o) s[t] += s[t + o];
    __syncthreads();
  }
  if (t == 0) bsum[blockIdx.x] = s[0];
}

// ---------------- phase 2 — single-block exclusive scan of block sums (B <= 1024) ----------------
__global__ void k_scan_bsum(int* __restrict__ bsum, int B) {
  __shared__ int s[1024];
  int t = threadIdx.x;
  int v = (t < B) ? bsum[t] : 0;
  s[t] = v;
  __syncthreads();
  for (int o = 1; o < 1024; o <<= 1) {
    int u = (t >= o) ? s[t - o] : 0;
    __syncthreads();
    s[t] += u;
    __syncthreads();
  }
  if (t < B) bsum[t] = s[t] - v;  // exclusive base per block
}

// ---------------- phase 3 — per-block local scan, write off/dinv ----------------
__global__ void k_scan_fin(const int* __restrict__ deg, const int* __restrict__ bsum,
                           int* __restrict__ off, float* __restrict__ dinv, int N) {
  __shared__ int s[256];
  int t = threadIdx.x;
  int n = blockIdx.x * 256 + t;
  int v = (n < N) ? deg[n] : 0;
  s[t] = v;
  __syncthreads();
  for (int o = 1; o < 256; o <<= 1) {
    int u = (t >= o) ? s[t - o] : 0;
    __syncthreads();
    s[t] += u;
    __syncthreads();
  }
  if (n < N) {
    int ex = bsum[blockIdx.x] + s[t] - v;  // exclusive prefix
    off[n] = ex;
    dinv[n] = rsqrtf((float)(v + 1));  // +1 self loop (GCN)
    if (n == N - 1) off[N] = ex + v;
  }
}

// ---------------- CSR fill pass A: bucketed, partition-local staging append ----------------
__global__ void k_stage(const int* __restrict__ src, const int* __restrict__ dst,
                        int* __restrict__ xcur, int2* __restrict__ stage,
                        int* __restrict__ ovf_cnt, int2* __restrict__ ovf, int NB, int E) {
  int part = blockIdx.x & (NPART - 1);
  int i = blockIdx.x * blockDim.x + threadIdx.x;
  int stride = gridDim.x * blockDim.x;
  for (int e = i; e < E; e += stride) {
    int s = src[e], d = dst[e];
    int b = d >> 8;  // NPB=256
    int pos = atomicAdd(&xcur[part * NB + b], 1);
    if (pos < CAP)
      stage[((size_t)(part * NB + b)) * CAP + pos] = make_int2(s, d);
    else {
      int op = atomicAdd(ovf_cnt, 1);
      if (op < OVCAP) ovf[op] = make_int2(s, d);
    }
  }
}

// ---------------- CSR fill pass B: block per bucket, LDS cursors, localized writes ----------------
__global__ void k_fill2(const int* __restrict__ off, const int* __restrict__ xcur,
                        const int2* __restrict__ stage, const int* __restrict__ ovf_cnt,
                        const int2* __restrict__ ovf, int* __restrict__ csr, int NB, int N) {
  __shared__ int cur_l[NPB];
  int b = blockIdx.x;
  int lo = b * NPB;
  int nn = min(NPB, N - lo);
  int t = threadIdx.x;
  if (t < nn) cur_l[t] = off[lo + t];
  __syncthreads();
  for (int part = 0; part < NPART; ++part) {
    int cnt = min(xcur[part * NB + b], CAP);
    const int2* seg = stage + ((size_t)(part * NB + b)) * CAP;
    for (int i = t; i < cnt; i += blockDim.x) {
      int2 e = seg[i];
      int pos = atomicAdd(&cur_l[e.y - lo], 1);
      csr[pos] = e.x;
    }
  }
  int oc = min(*ovf_cnt, OVCAP);
  for (int i = t; i < oc; i += blockDim.x) {
    int2 e = ovf[i];
    if (e.y >= lo && e.y < lo + nn) {
      int pos = atomicAdd(&cur_l[e.y - lo], 1);
      csr[pos] = e.x;
    }
  }
}

// ---------------- GEMM: out[n,f] = dinv[n] * sum_k X[n,k] * W[k,f] ----------------
template <int KOUT>
__global__ void k_gemm(const float* __restrict__ X, const float* __restrict__ W,
                       const float* __restrict__ dinv, float* __restrict__ out, int N) {
  int gtid = blockIdx.x * blockDim.x + threadIdx.x;
  int wave = gtid >> 6;
  int lane = threadIdx.x & 63;
  int nwaves = (gridDim.x * blockDim.x) >> 6;
  int f = lane & (KOUT - 1);
  float w[F];
#pragma unroll
  for (int k = 0; k < F; ++k) w[k] = W[k * KOUT + f];
  for (int n = wave; n < N; n += nwaves) {
    float xv = X[(size_t)n * F + lane];
    float acc = 0.f;
#pragma unroll
    for (int k = 0; k < F; ++k) acc += __shfl(xv, k, 64) * w[k];
    if (lane < KOUT) out[(size_t)n * KOUT + lane] = acc * dinv[n];
  }
}

// ---------------- GCN aggregation (vectorized): out[n] = dinv[n]*(sum_adj T[src] + T[n]) + b ----
template <int KOUT>
__global__ void k_agg(const float* __restrict__ T, const int* __restrict__ csr,
                      const int* __restrict__ off, const float* __restrict__ dinv,
                      const float* __restrict__ bias, float* __restrict__ out, int N) {
  constexpr int LPG = KOUT / 4;  // lanes per group
  constexpr int NG = 64 / LPG;   // edges processed per serial step
  int wave = (blockIdx.x * blockDim.x + threadIdx.x) >> 6;
  int lane = threadIdx.x & 63;
  if (wave >= N) return;
  int n = wave;
  int e0 = off[n], e1 = off[n + 1];
  int g = lane / LPG;
  int l = lane % LPG;
  float4 acc = make_float4(0.f, 0.f, 0.f, 0.f);
  for (int e = e0; e < e1; e += 64) {
    int se = (e + lane < e1) ? csr[e + lane] : -1;
    int nj = (min(64, e1 - e) + NG - 1) / NG;
    for (int j = 0; j < nj; ++j) {
      int s = __shfl(se, j * NG + g, 64);
      if (s >= 0) {
        float4 v = *(const float4*)&T[(size_t)s * KOUT + l * 4];
        acc.x += v.x; acc.y += v.y; acc.z += v.z; acc.w += v.w;
      }
    }
  }
#pragma unroll
  for (int o = LPG; o < 64; o <<= 1) {
    acc.x += __shfl_xor(acc.x, o, 64);
    acc.y += __shfl_xor(acc.y, o, 64);
    acc.z += __shfl_xor(acc.z, o, 64);
    acc.w += __shfl_xor(acc.w, o, 64);
  }
  if (g == 0) {
    float4 self = *(const float4*)&T[(size_t)n * KOUT + l * 4];
    float4 b4 = *(const float4*)&bias[l * 4];
    float dn = dinv[n];
    float4 r;
    r.x = (acc.x + self.x) * dn + b4.x;
    r.y = (acc.y + self.y) * dn + b4.y;
    r.z = (acc.z + self.z) * dn + b4.z;
    r.w = (acc.w + self.w) * dn + b4.w;
    *(float4*)&out[(size_t)n * KOUT + l * 4] = r;
  }
}

// ---------------- fused MFConv + policy aggregation: one gather of H rows ----------------
// MF:    val[n] = <sum_adj H[src], Wl[dc]> + <H[n], Wr[dc]> + bl[dc]
// pol:   u[n]   = dinv[n] * (sum_adj dinv[src]*H[src] + dinv[n]*H[n])   (W_pol deferred)
__global__ void k_mfpol(const float* __restrict__ H, const int* __restrict__ csr,
                        const int* __restrict__ off, const float* __restrict__ dinv,
                        const float* __restrict__ Wl, const float* __restrict__ bl,
                        const float* __restrict__ Wr, float* __restrict__ val,
                        float* __restrict__ u, int N) {
  int wave = (blockIdx.x * blockDim.x + threadIdx.x) >> 6;
  int lane = threadIdx.x & 63;
  if (wave >= N) return;
  int n = wave;
  int e0 = off[n], e1 = off[n + 1];
  int g = lane >> 4, l = lane & 15;
  float4 ah = make_float4(0.f, 0.f, 0.f, 0.f);
  float4 aw = make_float4(0.f, 0.f, 0.f, 0.f);
  for (int e = e0; e < e1; e += 64) {
    int idx = e + lane;
    int se = (idx < e1) ? csr[idx] : -1;
    float dv = (se >= 0) ? dinv[se] : 0.f;
    int nj = (min(64, e1 - e) + 3) >> 2;
    for (int j = 0; j < nj; ++j) {
      int sl = j * 4 + g;
      int s = __shfl(se, sl, 64);
      float dd = __shfl(dv, sl, 64);
      if (s >= 0) {
        float4 v = *(const float4*)&H[(size_t)s * F + l * 4];
        ah.x += v.x; ah.y += v.y; ah.z += v.z; ah.w += v.w;
        aw.x += dd * v.x; aw.y += dd * v.y; aw.z += dd * v.z; aw.w += dd * v.w;
      }
    }
  }
#pragma unroll
  for (int o = 16; o < 64; o <<= 1) {
    ah.x += __shfl_xor(ah.x, o, 64); ah.y += __shfl_xor(ah.y, o, 64);
    ah.z += __shfl_xor(ah.z, o, 64); ah.w += __shfl_xor(ah.w, o, 64);
    aw.x += __shfl_xor(aw.x, o, 64); aw.y += __shfl_xor(aw.y, o, 64);
    aw.z += __shfl_xor(aw.z, o, 64); aw.w += __shfl_xor(aw.w, o, 64);
  }
  int dc = min(e1 - e0, MAXD);
  float dn = dinv[n];
  float4 hn = *(const float4*)&H[(size_t)n * F + l * 4];
  float4 wl4 = *(const float4*)&Wl[dc * F + l * 4];
  float4 wr4 = *(const float4*)&Wr[dc * F + l * 4];
  float part = ah.x * wl4.x + ah.y * wl4.y + ah.z * wl4.z + ah.w * wl4.w
             + hn.x * wr4.x + hn.y * wr4.y + hn.z * wr4.z + hn.w * wr4.w;
#pragma unroll
  for (int o = 1; o < 16; o <<= 1) part += __shfl_xor(part, o, 64);
  if (lane == 0) val[n] = part + bl[dc];
  if (g == 0) {
    float4 r;
    r.x = (aw.x + dn * hn.x) * dn;
    r.y = (aw.y + dn * hn.y) * dn;
    r.z = (aw.z + dn * hn.z) * dn;
    r.w = (aw.w + dn * hn.w) * dn;
    *(float4*)&u[(size_t)n * F + l * 4] = r;
  }
}

// ---------------- pooling (batch sorted): per-block LDS accumulate of u (64f) + val + cnt ----
__global__ void k_pool2(const float* __restrict__ u, const float* __restrict__ valn,
                        const int* __restrict__ batch, float* __restrict__ Uacc,
                        float* __restrict__ valg, float* __restrict__ cntg, int N) {
  __shared__ float Ul[64 * F];
  __shared__ float Vl[64], Cl[64];
  int t = threadIdx.x;
  for (int i = t; i < 64 * F; i += 256) Ul[i] = 0.f;
  if (t < 64) { Vl[t] = 0.f; Cl[t] = 0.f; }
  __syncthreads();
  int base = blockIdx.x * 256;
  int f = t & 63, r = t >> 6;
  for (int i = r; i < 256; i += 4) {
    int n = base + i;
    if (n >= N) break;
    int g = batch[n];
    atomicAdd(&Ul[g * F + f], u[(size_t)n * F + f]);
    if (f == 0) { atomicAdd(&Vl[g], valn[n]); atomicAdd(&Cl[g], 1.f); }
  }
  __syncthreads();
  int last = min(base + 256, N) - 1;
  if (last < base) return;
  int gmin = batch[base], gmax = batch[last];
  int ng = gmax - gmin + 1;
  for (int idx = t; idx < ng * F; idx += 256) {
    int g = gmin + (idx >> 6), ff = idx & 63;
    atomicAdd(&Uacc[g * F + ff], Ul[g * F + ff]);
  }
  for (int idx = t; idx < ng; idx += 256) {
    int g = gmin + idx;
    atomicAdd(&valg[g], Vl[g]);
    atomicAdd(&cntg[g], Cl[g]);
  }
}

// ---------------- finalize: pol[g,p] = (U[g] @ W_pol)/cnt + b_pol ; copy val ----------------
__global__ void k_polfin(const float* __restrict__ Uacc, const float* __restrict__ valg,
                         const float* __restrict__ cntg, const float* __restrict__ W_pol,
                         const float* __restrict__ b_pol, float* __restrict__ out, int G) {
  int i = blockIdx.x * blockDim.x + threadIdx.x;
  if (i < G * P) {
    int g = i >> 5, p = i & 31;
    float s = 0.f;
#pragma unroll
    for (int k = 0; k < F; ++k) s += Uacc[g * F + k] * W_pol[k * P + p];
    out[i] = s / fmaxf(cntg[g], 1.f) + b_pol[p];
  }
  if (i < G) out[(size_t)G * P + i] = valg[i];
}

extern "C" void kernel_launch(void* const* d_in, const int* in_sizes, int n_in,
                              void* d_out, int out_size, void* d_ws, size_t ws_size,
                              hipStream_t stream) {
  const float* x = (const float*)d_in[0];
  const int* ei = (const int*)d_in[1];
  const int* batch = (const int*)d_in[2];
  const float* W_in = (const float*)d_in[3];
  const float* b_in = (const float*)d_in[4];
  const float* W1 = (const float*)d_in[5];
  const float* b1 = (const float*)d_in[6];
  const float* Wl = (const float*)d_in[7];
  const float* bl = (const float*)d_in[8];
  const float* Wr = (const float*)d_in[9];
  const float* W_pol = (const float*)d_in[10];
  const float* b_pol = (const float*)d_in[11];
  float* out = (float*)d_out;

  const int N = in_sizes[0] / F;
  const int E = in_sizes[1] / 2;
  const int G = out_size / (P + 1);
  const int* esrc = ei;
  const int* edst = ei + E;
  const int NB = (N + NPB - 1) / NPB;  // buckets == scan blocks (196)

  char* ws = (char*)d_ws;
  size_t o = 0;
  auto alloc = [&](size_t bytes) {
    char* r = ws + o;
    o = (o + bytes + 255) & ~(size_t)255;
    return r;
  };
  // ---- zero-init zone (single memset) ----
  char* zbase = ws;
  int* deg = (int*)alloc((size_t)N * 4);
  int* xcur = (int*)alloc((size_t)NPART * NB * 4);
  int* ovfc = (int*)alloc(4);
  float* Uacc = (float*)alloc((size_t)G * F * 4);
  float* valg = (float*)alloc((size_t)G * 4);
  float* cntg = (float*)alloc((size_t)G * 4);
  size_t zbytes = o;
  // ---- rest ----
  int* off = (int*)alloc((size_t)(N + 1) * 4);
  float* dinv = (float*)alloc((size_t)N * 4);
  int* csr = (int*)alloc((size_t)E * 4);
  int2* ovf = (int2*)alloc((size_t)OVCAP * 8);
  float* valn = (float*)alloc((size_t)N * 4);
  int* bsum = (int*)alloc(1024 * 4);
  float* bufA = (float*)alloc((size_t)N * F * 4);
  float* bufB = (float*)alloc((size_t)N * F * 4);
  int2* stage = (int2*)bufA;        // aliases bufA: dead before first k_gemm writes bufA
  float* u = bufA;                  // aliases bufA: live after gemm output t2 is dead
  (void)ws_size; (void)n_in;

  hipMemsetAsync(zbase, 0, zbytes, stream);

  const int bs = 256;
  k_count_deg<<<1024, bs, 0, stream>>>(edst, deg, E);
  k_bsum<<<NB, bs, 0, stream>>>(deg, bsum, N);
  k_scan_bsum<<<1, 1024, 0, stream>>>(bsum, NB);
  k_scan_fin<<<NB, bs, 0, stream>>>(deg, bsum, off, dinv, N);
  k_stage<<<1024, bs, 0, stream>>>(esrc, edst, xcur, stage, ovfc, ovf, NB, E);
  k_fill2<<<NB, bs, 0, stream>>>(off, xcur, stage, ovfc, ovf, csr, NB, N);

  int aggBlocks = (N * 64 + bs - 1) / bs;  // wave per node, 4 waves/block

  // conv_in
  k_gemm<F><<<2048, bs, 0, stream>>>(x, W_in, dinv, bufA, N);
  k_agg<F><<<aggBlocks, bs, 0, stream>>>(bufA, csr, off, dinv, b_in, bufB, N);
  // conv_1
  k_gemm<F><<<2048, bs, 0, stream>>>(bufB, W1, dinv, bufA, N);
  k_agg<F><<<aggBlocks, bs, 0, stream>>>(bufA, csr, off, dinv, b1, bufB, N);
  // fused conv_val (MFConv) + conv_policy aggregation (single gather of bufB rows)
  k_mfpol<<<aggBlocks, bs, 0, stream>>>(bufB, csr, off, dinv, Wl, bl, Wr, valn, u, N);

  int poolBlocks = (N + 255) / 256;
  k_pool2<<<poolBlocks, bs, 0, stream>>>(u, valn, batch, Uacc, valg, cntg, N);
  k_polfin<<<(G * P + bs - 1) / bs, bs, 0, stream>>>(Uacc, valg, cntg, W_pol, b_pol, out, G);
}

// Round 4
// 303.044 us; speedup vs baseline: 1.2372x; 1.2372x over previous
//
#include <hip/hip_runtime.h>

#define F 64
#define P 32
#define MAXD 10
#define NGRP 8  // dst-range groups, mapped to XCDs via blockIdx&7 (perf hint only)

// ---------------- degree count, XCD-partitioned by dst range ----------------
__global__ void k_count_deg(const int* __restrict__ dst, int* __restrict__ deg, int E, int N) {
  int r = blockIdx.x & (NGRP - 1);           // ~XCD id == dst range id
  float scale = (float)NGRP / (float)N;      // deterministic, same in all threads
  int gblk = blockIdx.x >> 3;
  int i = gblk * blockDim.x + threadIdx.x;
  int stride = (gridDim.x >> 3) * blockDim.x;
  int E4 = E >> 2;
  const int4* d4p = (const int4*)dst;
  for (int e4 = i; e4 < E4; e4 += stride) {
    int4 d4 = d4p[e4];
    int rr;
    rr = min(NGRP - 1, (int)((float)d4.x * scale)); if (rr == r) atomicAdd(&deg[d4.x], 1);
    rr = min(NGRP - 1, (int)((float)d4.y * scale)); if (rr == r) atomicAdd(&deg[d4.y], 1);
    rr = min(NGRP - 1, (int)((float)d4.z * scale)); if (rr == r) atomicAdd(&deg[d4.z], 1);
    rr = min(NGRP - 1, (int)((float)d4.w * scale)); if (rr == r) atomicAdd(&deg[d4.w], 1);
  }
  for (int e = (E & ~3) + i; e < E; e += stride) {
    int d = dst[e];
    int rr = min(NGRP - 1, (int)((float)d * scale));
    if (rr == r) atomicAdd(&deg[d], 1);
  }
}

// ---------------- hierarchical scan: phase 1 — per-block sums (256 nodes/block) ----------------
__global__ void k_bsum(const int* __restrict__ deg, int* __restrict__ bsum, int N) {
  __shared__ int s[256];
  int t = threadIdx.x;
  int n = blockIdx.x * 256 + t;
  s[t] = (n < N) ? deg[n] : 0;
  __syncthreads();
  for (int o = 128; o > 0; o >>= 1) {
    if (t < o) s[t] += s[t + o];
    __syncthreads();
  }
  if (t == 0) bsum[blockIdx.x] = s[0];
}

// ---------------- phase 2 — single-block exclusive scan of block sums (B <= 1024) ----------------
__global__ void k_scan_bsum(int* __restrict__ bsum, int B) {
  __shared__ int s[1024];
  int t = threadIdx.x;
  int v = (t < B) ? bsum[t] : 0;
  s[t] = v;
  __syncthreads();
  for (int o = 1; o < 1024; o <<= 1) {
    int u = (t >= o) ? s[t - o] : 0;
    __syncthreads();
    s[t] += u;
    __syncthreads();
  }
  if (t < B) bsum[t] = s[t] - v;  // exclusive base per block
}

// ---------------- phase 3 — per-block local scan, write off/cur/dinv ----------------
__global__ void k_scan_fin(const int* __restrict__ deg, const int* __restrict__ bsum,
                           int* __restrict__ off, int* __restrict__ cur,
                           float* __restrict__ dinv, int N) {
  __shared__ int s[256];
  int t = threadIdx.x;
  int n = blockIdx.x * 256 + t;
  int v = (n < N) ? deg[n] : 0;
  s[t] = v;
  __syncthreads();
  for (int o = 1; o < 256; o <<= 1) {
    int u = (t >= o) ? s[t - o] : 0;
    __syncthreads();
    s[t] += u;
    __syncthreads();
  }
  if (n < N) {
    int ex = bsum[blockIdx.x] + s[t] - v;  // exclusive prefix
    off[n] = ex;
    cur[n] = ex;
    dinv[n] = rsqrtf((float)(v + 1));  // +1 self loop (GCN)
    if (n == N - 1) off[N] = ex + v;
  }
}

// ---------------- CSR fill, XCD-partitioned: csr lines for range r written by one XCD ----------
__global__ void k_fill(const int* __restrict__ src, const int* __restrict__ dst,
                       int* __restrict__ cur, int* __restrict__ csr, int E, int N) {
  int r = blockIdx.x & (NGRP - 1);
  float scale = (float)NGRP / (float)N;
  int gblk = blockIdx.x >> 3;
  int i = gblk * blockDim.x + threadIdx.x;
  int stride = (gridDim.x >> 3) * blockDim.x;
  int E4 = E >> 2;
  const int4* d4p = (const int4*)dst;
  for (int e4 = i; e4 < E4; e4 += stride) {
    int4 d4 = d4p[e4];
    int e = e4 * 4;
    int rr;
    rr = min(NGRP - 1, (int)((float)d4.x * scale));
    if (rr == r) { int pos = atomicAdd(&cur[d4.x], 1); csr[pos] = src[e]; }
    rr = min(NGRP - 1, (int)((float)d4.y * scale));
    if (rr == r) { int pos = atomicAdd(&cur[d4.y], 1); csr[pos] = src[e + 1]; }
    rr = min(NGRP - 1, (int)((float)d4.z * scale));
    if (rr == r) { int pos = atomicAdd(&cur[d4.z], 1); csr[pos] = src[e + 2]; }
    rr = min(NGRP - 1, (int)((float)d4.w * scale));
    if (rr == r) { int pos = atomicAdd(&cur[d4.w], 1); csr[pos] = src[e + 3]; }
  }
  for (int e = (E & ~3) + i; e < E; e += stride) {
    int d = dst[e];
    int rr = min(NGRP - 1, (int)((float)d * scale));
    if (rr == r) { int pos = atomicAdd(&cur[d], 1); csr[pos] = src[e]; }
  }
}

// ---------------- GEMM: out[n,f] = dinv[n] * sum_k X[n,k] * W[k,f] ----------------
template <int KOUT>
__global__ void k_gemm(const float* __restrict__ X, const float* __restrict__ W,
                       const float* __restrict__ dinv, float* __restrict__ out, int N) {
  int gtid = blockIdx.x * blockDim.x + threadIdx.x;
  int wave = gtid >> 6;
  int lane = threadIdx.x & 63;
  int nwaves = (gridDim.x * blockDim.x) >> 6;
  int f = lane & (KOUT - 1);
  float w[F];
#pragma unroll
  for (int k = 0; k < F; ++k) w[k] = W[k * KOUT + f];
  for (int n = wave; n < N; n += nwaves) {
    float xv = X[(size_t)n * F + lane];
    float acc = 0.f;
#pragma unroll
    for (int k = 0; k < F; ++k) acc += __shfl(xv, k, 64) * w[k];
    if (lane < KOUT) out[(size_t)n * KOUT + lane] = acc * dinv[n];
  }
}

// ---------------- GCN aggregation (vectorized): out[n] = dinv[n]*(sum_adj T[src] + T[n]) + b ----
template <int KOUT>
__global__ void k_agg(const float* __restrict__ T, const int* __restrict__ csr,
                      const int* __restrict__ off, const float* __restrict__ dinv,
                      const float* __restrict__ bias, float* __restrict__ out, int N) {
  constexpr int LPG = KOUT / 4;  // lanes per group
  constexpr int NG = 64 / LPG;   // edges processed per serial step
  int wave = (blockIdx.x * blockDim.x + threadIdx.x) >> 6;
  int lane = threadIdx.x & 63;
  if (wave >= N) return;
  int n = wave;
  int e0 = off[n], e1 = off[n + 1];
  int g = lane / LPG;
  int l = lane % LPG;
  float4 acc = make_float4(0.f, 0.f, 0.f, 0.f);
  for (int e = e0; e < e1; e += 64) {
    int se = (e + lane < e1) ? csr[e + lane] : -1;
    int nj = (min(64, e1 - e) + NG - 1) / NG;
    for (int j = 0; j < nj; ++j) {
      int s = __shfl(se, j * NG + g, 64);
      if (s >= 0) {
        float4 v = *(const float4*)&T[(size_t)s * KOUT + l * 4];
        acc.x += v.x; acc.y += v.y; acc.z += v.z; acc.w += v.w;
      }
    }
  }
#pragma unroll
  for (int o = LPG; o < 64; o <<= 1) {
    acc.x += __shfl_xor(acc.x, o, 64);
    acc.y += __shfl_xor(acc.y, o, 64);
    acc.z += __shfl_xor(acc.z, o, 64);
    acc.w += __shfl_xor(acc.w, o, 64);
  }
  if (g == 0) {
    float4 self = *(const float4*)&T[(size_t)n * KOUT + l * 4];
    float4 b4 = *(const float4*)&bias[l * 4];
    float dn = dinv[n];
    float4 r;
    r.x = (acc.x + self.x) * dn + b4.x;
    r.y = (acc.y + self.y) * dn + b4.y;
    r.z = (acc.z + self.z) * dn + b4.z;
    r.w = (acc.w + self.w) * dn + b4.w;
    *(float4*)&out[(size_t)n * KOUT + l * 4] = r;
  }
}

// ---------------- fused MFConv + policy aggregation: one gather of H rows ----------------
// MF:    val[n] = <sum_adj H[src], Wl[dc]> + <H[n], Wr[dc]> + bl[dc]
// pol:   u[n]   = dinv[n] * (sum_adj dinv[src]*H[src] + dinv[n]*H[n])   (W_pol deferred)
__global__ void k_mfpol(const float* __restrict__ H, const int* __restrict__ csr,
                        const int* __restrict__ off, const float* __restrict__ dinv,
                        const float* __restrict__ Wl, const float* __restrict__ bl,
                        const float* __restrict__ Wr, float* __restrict__ val,
                        float* __restrict__ u, int N) {
  int wave = (blockIdx.x * blockDim.x + threadIdx.x) >> 6;
  int lane = threadIdx.x & 63;
  if (wave >= N) return;
  int n = wave;
  int e0 = off[n], e1 = off[n + 1];
  int g = lane >> 4, l = lane & 15;
  float4 ah = make_float4(0.f, 0.f, 0.f, 0.f);
  float4 aw = make_float4(0.f, 0.f, 0.f, 0.f);
  for (int e = e0; e < e1; e += 64) {
    int idx = e + lane;
    int se = (idx < e1) ? csr[idx] : -1;
    float dv = (se >= 0) ? dinv[se] : 0.f;
    int nj = (min(64, e1 - e) + 3) >> 2;
    for (int j = 0; j < nj; ++j) {
      int sl = j * 4 + g;
      int s = __shfl(se, sl, 64);
      float dd = __shfl(dv, sl, 64);
      if (s >= 0) {
        float4 v = *(const float4*)&H[(size_t)s * F + l * 4];
        ah.x += v.x; ah.y += v.y; ah.z += v.z; ah.w += v.w;
        aw.x += dd * v.x; aw.y += dd * v.y; aw.z += dd * v.z; aw.w += dd * v.w;
      }
    }
  }
#pragma unroll
  for (int o = 16; o < 64; o <<= 1) {
    ah.x += __shfl_xor(ah.x, o, 64); ah.y += __shfl_xor(ah.y, o, 64);
    ah.z += __shfl_xor(ah.z, o, 64); ah.w += __shfl_xor(ah.w, o, 64);
    aw.x += __shfl_xor(aw.x, o, 64); aw.y += __shfl_xor(aw.y, o, 64);
    aw.z += __shfl_xor(aw.z, o, 64); aw.w += __shfl_xor(aw.w, o, 64);
  }
  int dc = min(e1 - e0, MAXD);
  float dn = dinv[n];
  float4 hn = *(const float4*)&H[(size_t)n * F + l * 4];
  float4 wl4 = *(const float4*)&Wl[dc * F + l * 4];
  float4 wr4 = *(const float4*)&Wr[dc * F + l * 4];
  float part = ah.x * wl4.x + ah.y * wl4.y + ah.z * wl4.z + ah.w * wl4.w
             + hn.x * wr4.x + hn.y * wr4.y + hn.z * wr4.z + hn.w * wr4.w;
#pragma unroll
  for (int o = 1; o < 16; o <<= 1) part += __shfl_xor(part, o, 64);
  if (lane == 0) val[n] = part + bl[dc];
  if (g == 0) {
    float4 r;
    r.x = (aw.x + dn * hn.x) * dn;
    r.y = (aw.y + dn * hn.y) * dn;
    r.z = (aw.z + dn * hn.z) * dn;
    r.w = (aw.w + dn * hn.w) * dn;
    *(float4*)&u[(size_t)n * F + l * 4] = r;
  }
}

// ---------------- pooling (batch sorted): per-block LDS accumulate of u (64f) + val + cnt ----
__global__ void k_pool2(const float* __restrict__ u, const float* __restrict__ valn,
                        const int* __restrict__ batch, float* __restrict__ Uacc,
                        float* __restrict__ valg, float* __restrict__ cntg, int N) {
  __shared__ float Ul[64 * F];
  __shared__ float Vl[64], Cl[64];
  int t = threadIdx.x;
  for (int i = t; i < 64 * F; i += 256) Ul[i] = 0.f;
  if (t < 64) { Vl[t] = 0.f; Cl[t] = 0.f; }
  __syncthreads();
  int base = blockIdx.x * 256;
  int f = t & 63, r = t >> 6;
  for (int i = r; i < 256; i += 4) {
    int n = base + i;
    if (n >= N) break;
    int g = batch[n];
    atomicAdd(&Ul[g * F + f], u[(size_t)n * F + f]);
    if (f == 0) { atomicAdd(&Vl[g], valn[n]); atomicAdd(&Cl[g], 1.f); }
  }
  __syncthreads();
  int last = min(base + 256, N) - 1;
  if (last < base) return;
  int gmin = batch[base], gmax = batch[last];
  int ng = gmax - gmin + 1;
  for (int idx = t; idx < ng * F; idx += 256) {
    int g = gmin + (idx >> 6), ff = idx & 63;
    atomicAdd(&Uacc[g * F + ff], Ul[g * F + ff]);
  }
  for (int idx = t; idx < ng; idx += 256) {
    int g = gmin + idx;
    atomicAdd(&valg[g], Vl[g]);
    atomicAdd(&cntg[g], Cl[g]);
  }
}

// ---------------- finalize: pol[g,p] = (U[g] @ W_pol)/cnt + b_pol ; copy val ----------------
__global__ void k_polfin(const float* __restrict__ Uacc, const float* __restrict__ valg,
                         const float* __restrict__ cntg, const float* __restrict__ W_pol,
                         const float* __restrict__ b_pol, float* __restrict__ out, int G) {
  int i = blockIdx.x * blockDim.x + threadIdx.x;
  if (i < G * P) {
    int g = i >> 5, p = i & 31;
    float s = 0.f;
#pragma unroll
    for (int k = 0; k < F; ++k) s += Uacc[g * F + k] * W_pol[k * P + p];
    out[i] = s / fmaxf(cntg[g], 1.f) + b_pol[p];
  }
  if (i < G) out[(size_t)G * P + i] = valg[i];
}

extern "C" void kernel_launch(void* const* d_in, const int* in_sizes, int n_in,
                              void* d_out, int out_size, void* d_ws, size_t ws_size,
                              hipStream_t stream) {
  const float* x = (const float*)d_in[0];
  const int* ei = (const int*)d_in[1];
  const int* batch = (const int*)d_in[2];
  const float* W_in = (const float*)d_in[3];
  const float* b_in = (const float*)d_in[4];
  const float* W1 = (const float*)d_in[5];
  const float* b1 = (const float*)d_in[6];
  const float* Wl = (const float*)d_in[7];
  const float* bl = (const float*)d_in[8];
  const float* Wr = (const float*)d_in[9];
  const float* W_pol = (const float*)d_in[10];
  const float* b_pol = (const float*)d_in[11];
  float* out = (float*)d_out;

  const int N = in_sizes[0] / F;
  const int E = in_sizes[1] / 2;
  const int G = out_size / (P + 1);
  const int* esrc = ei;
  const int* edst = ei + E;
  const int NB = (N + 255) / 256;  // scan blocks (196)

  char* ws = (char*)d_ws;
  size_t o = 0;
  auto alloc = [&](size_t bytes) {
    char* r = ws + o;
    o = (o + bytes + 255) & ~(size_t)255;
    return r;
  };
  // ---- zero-init zone (single memset) ----
  char* zbase = ws;
  int* deg = (int*)alloc((size_t)N * 4);
  float* Uacc = (float*)alloc((size_t)G * F * 4);
  float* valg = (float*)alloc((size_t)G * 4);
  float* cntg = (float*)alloc((size_t)G * 4);
  size_t zbytes = o;
  // ---- rest ----
  int* off = (int*)alloc((size_t)(N + 1) * 4);
  int* cur = (int*)alloc((size_t)N * 4);
  float* dinv = (float*)alloc((size_t)N * 4);
  int* csr = (int*)alloc((size_t)E * 4);
  float* valn = (float*)alloc((size_t)N * 4);
  int* bsum = (int*)alloc(1024 * 4);
  float* bufA = (float*)alloc((size_t)N * F * 4);
  float* bufB = (float*)alloc((size_t)N * F * 4);
  float* u = bufA;  // aliases bufA: gemm output dead once mfpol writes u
  (void)ws_size; (void)n_in;

  hipMemsetAsync(zbase, 0, zbytes, stream);

  const int bs = 256;
  k_count_deg<<<2048, bs, 0, stream>>>(edst, deg, E, N);
  k_bsum<<<NB, bs, 0, stream>>>(deg, bsum, N);
  k_scan_bsum<<<1, 1024, 0, stream>>>(bsum, NB);
  k_scan_fin<<<NB, bs, 0, stream>>>(deg, bsum, off, cur, dinv, N);
  k_fill<<<2048, bs, 0, stream>>>(esrc, edst, cur, csr, E, N);

  int aggBlocks = (N * 64 + bs - 1) / bs;  // wave per node, 4 waves/block

  // conv_in
  k_gemm<F><<<2048, bs, 0, stream>>>(x, W_in, dinv, bufA, N);
  k_agg<F><<<aggBlocks, bs, 0, stream>>>(bufA, csr, off, dinv, b_in, bufB, N);
  // conv_1
  k_gemm<F><<<2048, bs, 0, stream>>>(bufB, W1, dinv, bufA, N);
  k_agg<F><<<aggBlocks, bs, 0, stream>>>(bufA, csr, off, dinv, b1, bufB, N);
  // fused conv_val (MFConv) + conv_policy aggregation (single gather of bufB rows)
  k_mfpol<<<aggBlocks, bs, 0, stream>>>(bufB, csr, off, dinv, Wl, bl, Wr, valn, u, N);

  int poolBlocks = (N + 255) / 256;
  k_pool2<<<poolBlocks, bs, 0, stream>>>(u, valn, batch, Uacc, valg, cntg, N);
  k_polfin<<<(G * P + bs - 1) / bs, bs, 0, stream>>>(Uacc, valg, cntg, W_pol, b_pol, out, G);
}

// Round 5
// 254.753 us; speedup vs baseline: 1.4717x; 1.1896x over previous
//
#include <hip/hip_runtime.h>

#define F 64
#define P 32
#define MAXD 10
#define NGRP 8  // dst-range groups, mapped to XCDs via blockIdx&7 (perf hint only)

// ---------------- degree count, XCD-partitioned by dst range ----------------
__global__ void k_count_deg(const int* __restrict__ dst, int* __restrict__ deg, int E, int N) {
  int r = blockIdx.x & (NGRP - 1);           // ~XCD id == dst range id
  float scale = (float)NGRP / (float)N;      // deterministic, same in all threads
  int gblk = blockIdx.x >> 3;
  int i = gblk * blockDim.x + threadIdx.x;
  int stride = (gridDim.x >> 3) * blockDim.x;
  int E4 = E >> 2;
  const int4* d4p = (const int4*)dst;
  for (int e4 = i; e4 < E4; e4 += stride) {
    int4 d4 = d4p[e4];
    int rr;
    rr = min(NGRP - 1, (int)((float)d4.x * scale)); if (rr == r) atomicAdd(&deg[d4.x], 1);
    rr = min(NGRP - 1, (int)((float)d4.y * scale)); if (rr == r) atomicAdd(&deg[d4.y], 1);
    rr = min(NGRP - 1, (int)((float)d4.z * scale)); if (rr == r) atomicAdd(&deg[d4.z], 1);
    rr = min(NGRP - 1, (int)((float)d4.w * scale)); if (rr == r) atomicAdd(&deg[d4.w], 1);
  }
  for (int e = (E & ~3) + i; e < E; e += stride) {
    int d = dst[e];
    int rr = min(NGRP - 1, (int)((float)d * scale));
    if (rr == r) atomicAdd(&deg[d], 1);
  }
}

// ---------------- hierarchical scan: phase 1 — per-block sums (256 nodes/block) ----------------
__global__ void k_bsum(const int* __restrict__ deg, int* __restrict__ bsum, int N) {
  __shared__ int s[256];
  int t = threadIdx.x;
  int n = blockIdx.x * 256 + t;
  s[t] = (n < N) ? deg[n] : 0;
  __syncthreads();
  for (int o = 128; o > 0; o >>= 1) {
    if (t < o) s[t] += s[t + o];
    __syncthreads();
  }
  if (t == 0) bsum[blockIdx.x] = s[0];
}

// ---------------- phase 2 — single-block exclusive scan of block sums (B <= 1024) ----------------
__global__ void k_scan_bsum(int* __restrict__ bsum, int B) {
  __shared__ int s[1024];
  int t = threadIdx.x;
  int v = (t < B) ? bsum[t] : 0;
  s[t] = v;
  __syncthreads();
  for (int o = 1; o < 1024; o <<= 1) {
    int u = (t >= o) ? s[t - o] : 0;
    __syncthreads();
    s[t] += u;
    __syncthreads();
  }
  if (t < B) bsum[t] = s[t] - v;  // exclusive base per block
}

// ---------------- phase 3 — per-block local scan, write off/cur/dinv ----------------
__global__ void k_scan_fin(const int* __restrict__ deg, const int* __restrict__ bsum,
                           int* __restrict__ off, int* __restrict__ cur,
                           float* __restrict__ dinv, int N) {
  __shared__ int s[256];
  int t = threadIdx.x;
  int n = blockIdx.x * 256 + t;
  int v = (n < N) ? deg[n] : 0;
  s[t] = v;
  __syncthreads();
  for (int o = 1; o < 256; o <<= 1) {
    int u = (t >= o) ? s[t - o] : 0;
    __syncthreads();
    s[t] += u;
    __syncthreads();
  }
  if (n < N) {
    int ex = bsum[blockIdx.x] + s[t] - v;  // exclusive prefix
    off[n] = ex;
    cur[n] = ex;
    dinv[n] = rsqrtf((float)(v + 1));  // +1 self loop (GCN)
    if (n == N - 1) off[N] = ex + v;
  }
}

// ---------------- CSR fill, XCD-partitioned: csr lines for range r written by one XCD ----------
__global__ void k_fill(const int* __restrict__ src, const int* __restrict__ dst,
                       int* __restrict__ cur, int* __restrict__ csr, int E, int N) {
  int r = blockIdx.x & (NGRP - 1);
  float scale = (float)NGRP / (float)N;
  int gblk = blockIdx.x >> 3;
  int i = gblk * blockDim.x + threadIdx.x;
  int stride = (gridDim.x >> 3) * blockDim.x;
  int E4 = E >> 2;
  const int4* d4p = (const int4*)dst;
  for (int e4 = i; e4 < E4; e4 += stride) {
    int4 d4 = d4p[e4];
    int e = e4 * 4;
    int rr;
    rr = min(NGRP - 1, (int)((float)d4.x * scale));
    if (rr == r) { int pos = atomicAdd(&cur[d4.x], 1); csr[pos] = src[e]; }
    rr = min(NGRP - 1, (int)((float)d4.y * scale));
    if (rr == r) { int pos = atomicAdd(&cur[d4.y], 1); csr[pos] = src[e + 1]; }
    rr = min(NGRP - 1, (int)((float)d4.z * scale));
    if (rr == r) { int pos = atomicAdd(&cur[d4.z], 1); csr[pos] = src[e + 2]; }
    rr = min(NGRP - 1, (int)((float)d4.w * scale));
    if (rr == r) { int pos = atomicAdd(&cur[d4.w], 1); csr[pos] = src[e + 3]; }
  }
  for (int e = (E & ~3) + i; e < E; e += stride) {
    int d = dst[e];
    int rr = min(NGRP - 1, (int)((float)d * scale));
    if (rr == r) { int pos = atomicAdd(&cur[d], 1); csr[pos] = src[e]; }
  }
}

// ---------------- xs = dinv[n] * x[n]  (pre-scale for linear GCN reorder) ----------------
__global__ void k_scale(const float* __restrict__ x, const float* __restrict__ dinv,
                        float* __restrict__ xs, int N) {
  int i = blockIdx.x * blockDim.x + threadIdx.x;
  int stride = gridDim.x * blockDim.x;
  int tot = N * (F / 4);
  const float4* x4 = (const float4*)x;
  float4* xs4 = (float4*)xs;
  for (int idx = i; idx < tot; idx += stride) {
    int n = idx >> 4;  // F/4 == 16 float4 per row
    float d = dinv[n];
    float4 v = x4[idx];
    v.x *= d; v.y *= d; v.z *= d; v.w *= d;
    xs4[idx] = v;
  }
}

// readlane broadcast of float4 component: lane k>>2, component k&3 (k compile-time const)
__device__ __forceinline__ float rdl(float4 v, int k) {
  float c = (k & 3) == 0 ? v.x : (k & 3) == 1 ? v.y : (k & 3) == 2 ? v.z : v.w;
  return __int_as_float(__builtin_amdgcn_readlane(__float_as_int(c), k >> 2));
}

// ---------------- fused GCN layer: gather + GEMV ----------------
// inner[n] = sum_{s in adj(n)} xs[s] + xs[n]   (xs pre-scaled by dinv)
// y[n,f]   = dinv[n] * <inner[n], W[:,f]> + b[f]
// WRITE_SCALED: store dinv[n]*y (next layer's pre-scaled input); else store y raw.
template <bool WRITE_SCALED>
__global__ void k_gcn(const float* __restrict__ xs, const int* __restrict__ csr,
                      const int* __restrict__ off, const float* __restrict__ dinv,
                      const float* __restrict__ W, const float* __restrict__ bias,
                      float* __restrict__ out, int N) {
  constexpr int NPW = 4;  // nodes per wave (amortizes W-column load)
  int wid = (blockIdx.x * blockDim.x + threadIdx.x) >> 6;
  int lane = threadIdx.x & 63;
  int nwaves = (gridDim.x * blockDim.x) >> 6;
  int g = lane >> 4, l = lane & 15;
  float w[F];
#pragma unroll
  for (int k = 0; k < F; ++k) w[k] = W[k * F + lane];  // W column `lane`
  float bv = bias[lane];
  for (int base = wid * NPW; base < N; base += nwaves * NPW) {
#pragma unroll 1
    for (int ni = 0; ni < NPW; ++ni) {
      int n = base + ni;
      if (n >= N) break;
      int e0 = off[n], e1 = off[n + 1];
      float4 acc;
      if (g == 0)
        acc = *(const float4*)&xs[(size_t)n * F + l * 4];  // self term (group 0 only)
      else
        acc = make_float4(0.f, 0.f, 0.f, 0.f);
      for (int e = e0; e < e1; e += 64) {
        int se = (e + lane < e1) ? csr[e + lane] : -1;
        int nj = (min(64, e1 - e) + 3) >> 2;
        for (int j = 0; j < nj; ++j) {
          int s = __shfl(se, j * 4 + g, 64);
          if (s >= 0) {
            float4 v = *(const float4*)&xs[(size_t)s * F + l * 4];
            acc.x += v.x; acc.y += v.y; acc.z += v.z; acc.w += v.w;
          }
        }
      }
#pragma unroll
      for (int o = 16; o < 64; o <<= 1) {  // butterfly: all lanes get full group-sum
        acc.x += __shfl_xor(acc.x, o, 64);
        acc.y += __shfl_xor(acc.y, o, 64);
        acc.z += __shfl_xor(acc.z, o, 64);
        acc.w += __shfl_xor(acc.w, o, 64);
      }
      // GEMV: every lane has inner[l*4..l*4+3]; broadcast via readlane (VALU, no LDS pipe)
      float y0 = 0.f, y1 = 0.f, y2 = 0.f, y3 = 0.f;
#pragma unroll
      for (int k = 0; k < F; k += 4) {
        y0 += rdl(acc, k) * w[k];
        y1 += rdl(acc, k + 1) * w[k + 1];
        y2 += rdl(acc, k + 2) * w[k + 2];
        y3 += rdl(acc, k + 3) * w[k + 3];
      }
      float dn = dinv[n];
      float y = dn * ((y0 + y1) + (y2 + y3)) + bv;
      if (WRITE_SCALED) y *= dn;
      out[(size_t)n * F + lane] = y;
    }
  }
}

// ---------------- fused MFConv + policy aggregation: one gather of H rows ----------------
// MF:    val[n] = <sum_adj H[src], Wl[dc]> + <H[n], Wr[dc]> + bl[dc]
// pol:   u[n]   = dinv[n] * (sum_adj dinv[src]*H[src] + dinv[n]*H[n])   (W_pol deferred)
__global__ void k_mfpol(const float* __restrict__ H, const int* __restrict__ csr,
                        const int* __restrict__ off, const float* __restrict__ dinv,
                        const float* __restrict__ Wl, const float* __restrict__ bl,
                        const float* __restrict__ Wr, float* __restrict__ val,
                        float* __restrict__ u, int N) {
  int wave = (blockIdx.x * blockDim.x + threadIdx.x) >> 6;
  int lane = threadIdx.x & 63;
  if (wave >= N) return;
  int n = wave;
  int e0 = off[n], e1 = off[n + 1];
  int g = lane >> 4, l = lane & 15;
  float4 ah = make_float4(0.f, 0.f, 0.f, 0.f);
  float4 aw = make_float4(0.f, 0.f, 0.f, 0.f);
  for (int e = e0; e < e1; e += 64) {
    int idx = e + lane;
    int se = (idx < e1) ? csr[idx] : -1;
    float dv = (se >= 0) ? dinv[se] : 0.f;
    int nj = (min(64, e1 - e) + 3) >> 2;
    for (int j = 0; j < nj; ++j) {
      int sl = j * 4 + g;
      int s = __shfl(se, sl, 64);
      float dd = __shfl(dv, sl, 64);
      if (s >= 0) {
        float4 v = *(const float4*)&H[(size_t)s * F + l * 4];
        ah.x += v.x; ah.y += v.y; ah.z += v.z; ah.w += v.w;
        aw.x += dd * v.x; aw.y += dd * v.y; aw.z += dd * v.z; aw.w += dd * v.w;
      }
    }
  }
#pragma unroll
  for (int o = 16; o < 64; o <<= 1) {
    ah.x += __shfl_xor(ah.x, o, 64); ah.y += __shfl_xor(ah.y, o, 64);
    ah.z += __shfl_xor(ah.z, o, 64); ah.w += __shfl_xor(ah.w, o, 64);
    aw.x += __shfl_xor(aw.x, o, 64); aw.y += __shfl_xor(aw.y, o, 64);
    aw.z += __shfl_xor(aw.z, o, 64); aw.w += __shfl_xor(aw.w, o, 64);
  }
  int dc = min(e1 - e0, MAXD);
  float dn = dinv[n];
  float4 hn = *(const float4*)&H[(size_t)n * F + l * 4];
  float4 wl4 = *(const float4*)&Wl[dc * F + l * 4];
  float4 wr4 = *(const float4*)&Wr[dc * F + l * 4];
  float part = ah.x * wl4.x + ah.y * wl4.y + ah.z * wl4.z + ah.w * wl4.w
             + hn.x * wr4.x + hn.y * wr4.y + hn.z * wr4.z + hn.w * wr4.w;
#pragma unroll
  for (int o = 1; o < 16; o <<= 1) part += __shfl_xor(part, o, 64);
  if (lane == 0) val[n] = part + bl[dc];
  if (g == 0) {
    float4 r;
    r.x = (aw.x + dn * hn.x) * dn;
    r.y = (aw.y + dn * hn.y) * dn;
    r.z = (aw.z + dn * hn.z) * dn;
    r.w = (aw.w + dn * hn.w) * dn;
    *(float4*)&u[(size_t)n * F + l * 4] = r;
  }
}

// ---------------- pooling (batch sorted): per-block LDS accumulate of u (64f) + val + cnt ----
__global__ void k_pool2(const float* __restrict__ u, const float* __restrict__ valn,
                        const int* __restrict__ batch, float* __restrict__ Uacc,
                        float* __restrict__ valg, float* __restrict__ cntg, int N) {
  __shared__ float Ul[64 * F];
  __shared__ float Vl[64], Cl[64];
  int t = threadIdx.x;
  for (int i = t; i < 64 * F; i += 256) Ul[i] = 0.f;
  if (t < 64) { Vl[t] = 0.f; Cl[t] = 0.f; }
  __syncthreads();
  int base = blockIdx.x * 256;
  int f = t & 63, r = t >> 6;
  for (int i = r; i < 256; i += 4) {
    int n = base + i;
    if (n >= N) break;
    int g = batch[n];
    atomicAdd(&Ul[g * F + f], u[(size_t)n * F + f]);
    if (f == 0) { atomicAdd(&Vl[g], valn[n]); atomicAdd(&Cl[g], 1.f); }
  }
  __syncthreads();
  int last = min(base + 256, N) - 1;
  if (last < base) return;
  int gmin = batch[base], gmax = batch[last];
  int ng = gmax - gmin + 1;
  for (int idx = t; idx < ng * F; idx += 256) {
    int g = gmin + (idx >> 6), ff = idx & 63;
    atomicAdd(&Uacc[g * F + ff], Ul[g * F + ff]);
  }
  for (int idx = t; idx < ng; idx += 256) {
    int g = gmin + idx;
    atomicAdd(&valg[g], Vl[g]);
    atomicAdd(&cntg[g], Cl[g]);
  }
}

// ---------------- finalize: pol[g,p] = (U[g] @ W_pol)/cnt + b_pol ; copy val ----------------
__global__ void k_polfin(const float* __restrict__ Uacc, const float* __restrict__ valg,
                         const float* __restrict__ cntg, const float* __restrict__ W_pol,
                         const float* __restrict__ b_pol, float* __restrict__ out, int G) {
  int i = blockIdx.x * blockDim.x + threadIdx.x;
  if (i < G * P) {
    int g = i >> 5, p = i & 31;
    float s = 0.f;
#pragma unroll
    for (int k = 0; k < F; ++k) s += Uacc[g * F + k] * W_pol[k * P + p];
    out[i] = s / fmaxf(cntg[g], 1.f) + b_pol[p];
  }
  if (i < G) out[(size_t)G * P + i] = valg[i];
}

extern "C" void kernel_launch(void* const* d_in, const int* in_sizes, int n_in,
                              void* d_out, int out_size, void* d_ws, size_t ws_size,
                              hipStream_t stream) {
  const float* x = (const float*)d_in[0];
  const int* ei = (const int*)d_in[1];
  const int* batch = (const int*)d_in[2];
  const float* W_in = (const float*)d_in[3];
  const float* b_in = (const float*)d_in[4];
  const float* W1 = (const float*)d_in[5];
  const float* b1 = (const float*)d_in[6];
  const float* Wl = (const float*)d_in[7];
  const float* bl = (const float*)d_in[8];
  const float* Wr = (const float*)d_in[9];
  const float* W_pol = (const float*)d_in[10];
  const float* b_pol = (const float*)d_in[11];
  float* out = (float*)d_out;

  const int N = in_sizes[0] / F;
  const int E = in_sizes[1] / 2;
  const int G = out_size / (P + 1);
  const int* esrc = ei;
  const int* edst = ei + E;
  const int NB = (N + 255) / 256;  // scan blocks (196)

  char* ws = (char*)d_ws;
  size_t o = 0;
  auto alloc = [&](size_t bytes) {
    char* r = ws + o;
    o = (o + bytes + 255) & ~(size_t)255;
    return r;
  };
  // ---- zero-init zone (single memset) ----
  char* zbase = ws;
  int* deg = (int*)alloc((size_t)N * 4);
  float* Uacc = (float*)alloc((size_t)G * F * 4);
  float* valg = (float*)alloc((size_t)G * 4);
  float* cntg = (float*)alloc((size_t)G * 4);
  size_t zbytes = o;
  // ---- rest ----
  int* off = (int*)alloc((size_t)(N + 1) * 4);
  int* cur = (int*)alloc((size_t)N * 4);
  float* dinv = (float*)alloc((size_t)N * 4);
  int* csr = (int*)alloc((size_t)E * 4);
  float* valn = (float*)alloc((size_t)N * 4);
  int* bsum = (int*)alloc(1024 * 4);
  float* bufA = (float*)alloc((size_t)N * F * 4);  // xs1, then h2
  float* bufB = (float*)alloc((size_t)N * F * 4);  // xs2 (=dinv*h1), then u
  (void)ws_size; (void)n_in;

  hipMemsetAsync(zbase, 0, zbytes, stream);

  const int bs = 256;
  k_count_deg<<<2048, bs, 0, stream>>>(edst, deg, E, N);
  k_bsum<<<NB, bs, 0, stream>>>(deg, bsum, N);
  k_scan_bsum<<<1, 1024, 0, stream>>>(bsum, NB);
  k_scan_fin<<<NB, bs, 0, stream>>>(deg, bsum, off, cur, dinv, N);
  k_fill<<<2048, bs, 0, stream>>>(esrc, edst, cur, csr, E, N);

  // xs1 = dinv * x
  k_scale<<<2048, bs, 0, stream>>>(x, dinv, bufA, N);

  // layer 1: gather xs1, GEMV W_in, write dinv*h1 (= xs2) into bufB
  int gcnBlocks = (N + 4 * 4 - 1) / (4 * 4);  // NPW=4, 4 waves/block
  k_gcn<true><<<gcnBlocks, bs, 0, stream>>>(bufA, csr, off, dinv, W_in, b_in, bufB, N);
  // layer 2: gather xs2, GEMV W1, write raw h2 into bufA
  k_gcn<false><<<gcnBlocks, bs, 0, stream>>>(bufB, csr, off, dinv, W1, b1, bufA, N);

  // fused conv_val (MFConv) + conv_policy aggregation (single gather of h2 rows)
  int aggBlocks = (N * 64 + bs - 1) / bs;  // wave per node
  k_mfpol<<<aggBlocks, bs, 0, stream>>>(bufA, csr, off, dinv, Wl, bl, Wr, valn, bufB, N);

  int poolBlocks = (N + 255) / 256;
  k_pool2<<<poolBlocks, bs, 0, stream>>>(bufB, valn, batch, Uacc, valg, cntg, N);
  k_polfin<<<(G * P + bs - 1) / bs, bs, 0, stream>>>(Uacc, valg, cntg, W_pol, b_pol, out, G);
}

// Round 6
// 250.979 us; speedup vs baseline: 1.4938x; 1.0150x over previous
//
#include <hip/hip_runtime.h>

#define F 64
#define P 32
#define MAXD 10
#define NGRP 8  // dst-range groups, mapped to XCDs via blockIdx&7 (perf hint only)

// ---------------- degree count, XCD-partitioned by dst range ----------------
__global__ void k_count_deg(const int* __restrict__ dst, int* __restrict__ deg, int E, int N) {
  int r = blockIdx.x & (NGRP - 1);           // ~XCD id == dst range id
  float scale = (float)NGRP / (float)N;      // deterministic, same in all threads
  int gblk = blockIdx.x >> 3;
  int i = gblk * blockDim.x + threadIdx.x;
  int stride = (gridDim.x >> 3) * blockDim.x;
  int E4 = E >> 2;
  const int4* d4p = (const int4*)dst;
  for (int e4 = i; e4 < E4; e4 += stride) {
    int4 d4 = d4p[e4];
    int rr;
    rr = min(NGRP - 1, (int)((float)d4.x * scale)); if (rr == r) atomicAdd(&deg[d4.x], 1);
    rr = min(NGRP - 1, (int)((float)d4.y * scale)); if (rr == r) atomicAdd(&deg[d4.y], 1);
    rr = min(NGRP - 1, (int)((float)d4.z * scale)); if (rr == r) atomicAdd(&deg[d4.z], 1);
    rr = min(NGRP - 1, (int)((float)d4.w * scale)); if (rr == r) atomicAdd(&deg[d4.w], 1);
  }
  for (int e = (E & ~3) + i; e < E; e += stride) {
    int d = dst[e];
    int rr = min(NGRP - 1, (int)((float)d * scale));
    if (rr == r) atomicAdd(&deg[d], 1);
  }
}

// ---------------- hierarchical scan: phase 1 — per-block sums (256 nodes/block) ----------------
__global__ void k_bsum(const int* __restrict__ deg, int* __restrict__ bsum, int N) {
  __shared__ int s[256];
  int t = threadIdx.x;
  int n = blockIdx.x * 256 + t;
  s[t] = (n < N) ? deg[n] : 0;
  __syncthreads();
  for (int o = 128; o > 0; o >>= 1) {
    if (t < o) s[t] += s[t + o];
    __syncthreads();
  }
  if (t == 0) bsum[blockIdx.x] = s[0];
}

// ---------------- phase 2 — single-block exclusive scan of block sums (B <= 1024) ----------------
__global__ void k_scan_bsum(int* __restrict__ bsum, int B) {
  __shared__ int s[1024];
  int t = threadIdx.x;
  int v = (t < B) ? bsum[t] : 0;
  s[t] = v;
  __syncthreads();
  for (int o = 1; o < 1024; o <<= 1) {
    int u = (t >= o) ? s[t - o] : 0;
    __syncthreads();
    s[t] += u;
    __syncthreads();
  }
  if (t < B) bsum[t] = s[t] - v;  // exclusive base per block
}

// ---------------- phase 3 — per-block local scan, write off/cur/dinv ----------------
__global__ void k_scan_fin(const int* __restrict__ deg, const int* __restrict__ bsum,
                           int* __restrict__ off, int* __restrict__ cur,
                           float* __restrict__ dinv, int N) {
  __shared__ int s[256];
  int t = threadIdx.x;
  int n = blockIdx.x * 256 + t;
  int v = (n < N) ? deg[n] : 0;
  s[t] = v;
  __syncthreads();
  for (int o = 1; o < 256; o <<= 1) {
    int u = (t >= o) ? s[t - o] : 0;
    __syncthreads();
    s[t] += u;
    __syncthreads();
  }
  if (n < N) {
    int ex = bsum[blockIdx.x] + s[t] - v;  // exclusive prefix
    off[n] = ex;
    cur[n] = ex;
    dinv[n] = rsqrtf((float)(v + 1));  // +1 self loop (GCN)
    if (n == N - 1) off[N] = ex + v;
  }
}

// ---------------- CSR fill, XCD-partitioned: csr lines for range r written by one XCD ----------
__global__ void k_fill(const int* __restrict__ src, const int* __restrict__ dst,
                       int* __restrict__ cur, int* __restrict__ csr, int E, int N) {
  int r = blockIdx.x & (NGRP - 1);
  float scale = (float)NGRP / (float)N;
  int gblk = blockIdx.x >> 3;
  int i = gblk * blockDim.x + threadIdx.x;
  int stride = (gridDim.x >> 3) * blockDim.x;
  int E4 = E >> 2;
  const int4* d4p = (const int4*)dst;
  for (int e4 = i; e4 < E4; e4 += stride) {
    int4 d4 = d4p[e4];
    int e = e4 * 4;
    int rr;
    rr = min(NGRP - 1, (int)((float)d4.x * scale));
    if (rr == r) { int pos = atomicAdd(&cur[d4.x], 1); csr[pos] = src[e]; }
    rr = min(NGRP - 1, (int)((float)d4.y * scale));
    if (rr == r) { int pos = atomicAdd(&cur[d4.y], 1); csr[pos] = src[e + 1]; }
    rr = min(NGRP - 1, (int)((float)d4.z * scale));
    if (rr == r) { int pos = atomicAdd(&cur[d4.z], 1); csr[pos] = src[e + 2]; }
    rr = min(NGRP - 1, (int)((float)d4.w * scale));
    if (rr == r) { int pos = atomicAdd(&cur[d4.w], 1); csr[pos] = src[e + 3]; }
  }
  for (int e = (E & ~3) + i; e < E; e += stride) {
    int d = dst[e];
    int rr = min(NGRP - 1, (int)((float)d * scale));
    if (rr == r) { int pos = atomicAdd(&cur[d], 1); csr[pos] = src[e]; }
  }
}

// ---------------- xs = dinv[n] * x[n]  (pre-scale for linear GCN reorder) ----------------
__global__ void k_scale(const float* __restrict__ x, const float* __restrict__ dinv,
                        float* __restrict__ xs, int N) {
  int i = blockIdx.x * blockDim.x + threadIdx.x;
  int stride = gridDim.x * blockDim.x;
  int tot = N * (F / 4);
  const float4* x4 = (const float4*)x;
  float4* xs4 = (float4*)xs;
  for (int idx = i; idx < tot; idx += stride) {
    int n = idx >> 4;  // F/4 == 16 float4 per row
    float d = dinv[n];
    float4 v = x4[idx];
    v.x *= d; v.y *= d; v.z *= d; v.w *= d;
    xs4[idx] = v;
  }
}

// readlane broadcast of float4 component: lane k>>2, component k&3 (k compile-time const)
__device__ __forceinline__ float rdl(float4 v, int k) {
  float c = (k & 3) == 0 ? v.x : (k & 3) == 1 ? v.y : (k & 3) == 2 ? v.z : v.w;
  return __int_as_float(__builtin_amdgcn_readlane(__float_as_int(c), k >> 2));
}

// ---------------- fused GCN layer: gather + GEMV (persistent grid for full occupancy) ----------
// inner[n] = sum_{s in adj(n)} xs[s] + xs[n]   (xs pre-scaled by dinv)
// y[n,f]   = dinv[n] * <inner[n], W[:,f]> + b[f]
// WRITE_SCALED: store dinv[n]*y (next layer's pre-scaled input); else store y raw.
template <bool WRITE_SCALED>
__global__ void k_gcn(const float* __restrict__ xs, const int* __restrict__ csr,
                      const int* __restrict__ off, const float* __restrict__ dinv,
                      const float* __restrict__ W, const float* __restrict__ bias,
                      float* __restrict__ out, int N) {
  constexpr int NPW = 4;  // nodes per wave chunk (amortizes W-column load)
  int wid = (blockIdx.x * blockDim.x + threadIdx.x) >> 6;
  int lane = threadIdx.x & 63;
  int nwaves = (gridDim.x * blockDim.x) >> 6;
  int g = lane >> 4, l = lane & 15;
  float w[F];
#pragma unroll
  for (int k = 0; k < F; ++k) w[k] = W[k * F + lane];  // W column `lane`
  float bv = bias[lane];
  for (int base = wid * NPW; base < N; base += nwaves * NPW) {
#pragma unroll 1
    for (int ni = 0; ni < NPW; ++ni) {
      int n = base + ni;
      if (n >= N) break;
      int e0 = off[n], e1 = off[n + 1];
      float4 acc;
      if (g == 0)
        acc = *(const float4*)&xs[(size_t)n * F + l * 4];  // self term (group 0 only)
      else
        acc = make_float4(0.f, 0.f, 0.f, 0.f);
      for (int e = e0; e < e1; e += 64) {
        int se = (e + lane < e1) ? csr[e + lane] : -1;
        int nj = (min(64, e1 - e) + 3) >> 2;
        for (int j = 0; j < nj; ++j) {
          int s = __shfl(se, j * 4 + g, 64);
          if (s >= 0) {
            float4 v = *(const float4*)&xs[(size_t)s * F + l * 4];
            acc.x += v.x; acc.y += v.y; acc.z += v.z; acc.w += v.w;
          }
        }
      }
#pragma unroll
      for (int o = 16; o < 64; o <<= 1) {  // butterfly: all lanes get full group-sum
        acc.x += __shfl_xor(acc.x, o, 64);
        acc.y += __shfl_xor(acc.y, o, 64);
        acc.z += __shfl_xor(acc.z, o, 64);
        acc.w += __shfl_xor(acc.w, o, 64);
      }
      // GEMV: every lane has inner[l*4..l*4+3]; broadcast via readlane (VALU, no LDS pipe)
      float y0 = 0.f, y1 = 0.f, y2 = 0.f, y3 = 0.f;
#pragma unroll
      for (int k = 0; k < F; k += 4) {
        y0 += rdl(acc, k) * w[k];
        y1 += rdl(acc, k + 1) * w[k + 1];
        y2 += rdl(acc, k + 2) * w[k + 2];
        y3 += rdl(acc, k + 3) * w[k + 3];
      }
      float dn = dinv[n];
      float y = dn * ((y0 + y1) + (y2 + y3)) + bv;
      if (WRITE_SCALED) y *= dn;
      out[(size_t)n * F + lane] = y;
    }
  }
}

// ---------------- fused MFConv + policy aggregation: one gather of H rows ----------------
// MF:    val[n] = <sum_adj H[src], Wl[dc]> + <H[n], Wr[dc]> + bl[dc]
// pol:   u[n]   = dinv[n] * (sum_adj dinv[src]*H[src] + dinv[n]*H[n])   (W_pol deferred)
__global__ void k_mfpol(const float* __restrict__ H, const int* __restrict__ csr,
                        const int* __restrict__ off, const float* __restrict__ dinv,
                        const float* __restrict__ Wl, const float* __restrict__ bl,
                        const float* __restrict__ Wr, float* __restrict__ val,
                        float* __restrict__ u, int N) {
  int wave = (blockIdx.x * blockDim.x + threadIdx.x) >> 6;
  int lane = threadIdx.x & 63;
  if (wave >= N) return;
  int n = wave;
  int e0 = off[n], e1 = off[n + 1];
  int g = lane >> 4, l = lane & 15;
  float4 ah = make_float4(0.f, 0.f, 0.f, 0.f);
  float4 aw = make_float4(0.f, 0.f, 0.f, 0.f);
  for (int e = e0; e < e1; e += 64) {
    int idx = e + lane;
    int se = (idx < e1) ? csr[idx] : -1;
    float dv = (se >= 0) ? dinv[se] : 0.f;
    int nj = (min(64, e1 - e) + 3) >> 2;
    for (int j = 0; j < nj; ++j) {
      int sl = j * 4 + g;
      int s = __shfl(se, sl, 64);
      float dd = __shfl(dv, sl, 64);
      if (s >= 0) {
        float4 v = *(const float4*)&H[(size_t)s * F + l * 4];
        ah.x += v.x; ah.y += v.y; ah.z += v.z; ah.w += v.w;
        aw.x += dd * v.x; aw.y += dd * v.y; aw.z += dd * v.z; aw.w += dd * v.w;
      }
    }
  }
#pragma unroll
  for (int o = 16; o < 64; o <<= 1) {
    ah.x += __shfl_xor(ah.x, o, 64); ah.y += __shfl_xor(ah.y, o, 64);
    ah.z += __shfl_xor(ah.z, o, 64); ah.w += __shfl_xor(ah.w, o, 64);
    aw.x += __shfl_xor(aw.x, o, 64); aw.y += __shfl_xor(aw.y, o, 64);
    aw.z += __shfl_xor(aw.z, o, 64); aw.w += __shfl_xor(aw.w, o, 64);
  }
  int dc = min(e1 - e0, MAXD);
  float dn = dinv[n];
  float4 hn = *(const float4*)&H[(size_t)n * F + l * 4];
  float4 wl4 = *(const float4*)&Wl[dc * F + l * 4];
  float4 wr4 = *(const float4*)&Wr[dc * F + l * 4];
  float part = ah.x * wl4.x + ah.y * wl4.y + ah.z * wl4.z + ah.w * wl4.w
             + hn.x * wr4.x + hn.y * wr4.y + hn.z * wr4.z + hn.w * wr4.w;
#pragma unroll
  for (int o = 1; o < 16; o <<= 1) part += __shfl_xor(part, o, 64);
  if (lane == 0) val[n] = part + bl[dc];
  if (g == 0) {
    float4 r;
    r.x = (aw.x + dn * hn.x) * dn;
    r.y = (aw.y + dn * hn.y) * dn;
    r.z = (aw.z + dn * hn.z) * dn;
    r.w = (aw.w + dn * hn.w) * dn;
    *(float4*)&u[(size_t)n * F + l * 4] = r;
  }
}

// ---------------- pooling (batch sorted): per-block LDS accumulate of u (64f) + val + cnt ----
__global__ void k_pool2(const float* __restrict__ u, const float* __restrict__ valn,
                        const int* __restrict__ batch, float* __restrict__ Uacc,
                        float* __restrict__ valg, float* __restrict__ cntg, int N) {
  __shared__ float Ul[64 * F];
  __shared__ float Vl[64], Cl[64];
  int t = threadIdx.x;
  for (int i = t; i < 64 * F; i += 256) Ul[i] = 0.f;
  if (t < 64) { Vl[t] = 0.f; Cl[t] = 0.f; }
  __syncthreads();
  int base = blockIdx.x * 256;
  int f = t & 63, r = t >> 6;
  for (int i = r; i < 256; i += 4) {
    int n = base + i;
    if (n >= N) break;
    int g = batch[n];
    atomicAdd(&Ul[g * F + f], u[(size_t)n * F + f]);
    if (f == 0) { atomicAdd(&Vl[g], valn[n]); atomicAdd(&Cl[g], 1.f); }
  }
  __syncthreads();
  int last = min(base + 256, N) - 1;
  if (last < base) return;
  int gmin = batch[base], gmax = batch[last];
  int ng = gmax - gmin + 1;
  for (int idx = t; idx < ng * F; idx += 256) {
    int g = gmin + (idx >> 6), ff = idx & 63;
    atomicAdd(&Uacc[g * F + ff], Ul[g * F + ff]);
  }
  for (int idx = t; idx < ng; idx += 256) {
    int g = gmin + idx;
    atomicAdd(&valg[g], Vl[g]);
    atomicAdd(&cntg[g], Cl[g]);
  }
}

// ---------------- finalize: pol[g,p] = (U[g] @ W_pol)/cnt + b_pol ; copy val ----------------
__global__ void k_polfin(const float* __restrict__ Uacc, const float* __restrict__ valg,
                         const float* __restrict__ cntg, const float* __restrict__ W_pol,
                         const float* __restrict__ b_pol, float* __restrict__ out, int G) {
  int i = blockIdx.x * blockDim.x + threadIdx.x;
  if (i < G * P) {
    int g = i >> 5, p = i & 31;
    float s = 0.f;
#pragma unroll
    for (int k = 0; k < F; ++k) s += Uacc[g * F + k] * W_pol[k * P + p];
    out[i] = s / fmaxf(cntg[g], 1.f) + b_pol[p];
  }
  if (i < G) out[(size_t)G * P + i] = valg[i];
}

extern "C" void kernel_launch(void* const* d_in, const int* in_sizes, int n_in,
                              void* d_out, int out_size, void* d_ws, size_t ws_size,
                              hipStream_t stream) {
  const float* x = (const float*)d_in[0];
  const int* ei = (const int*)d_in[1];
  const int* batch = (const int*)d_in[2];
  const float* W_in = (const float*)d_in[3];
  const float* b_in = (const float*)d_in[4];
  const float* W1 = (const float*)d_in[5];
  const float* b1 = (const float*)d_in[6];
  const float* Wl = (const float*)d_in[7];
  const float* bl = (const float*)d_in[8];
  const float* Wr = (const float*)d_in[9];
  const float* W_pol = (const float*)d_in[10];
  const float* b_pol = (const float*)d_in[11];
  float* out = (float*)d_out;

  const int N = in_sizes[0] / F;
  const int E = in_sizes[1] / 2;
  const int G = out_size / (P + 1);
  const int* esrc = ei;
  const int* edst = ei + E;
  const int NB = (N + 255) / 256;  // scan blocks (196)

  char* ws = (char*)d_ws;
  size_t o = 0;
  auto alloc = [&](size_t bytes) {
    char* r = ws + o;
    o = (o + bytes + 255) & ~(size_t)255;
    return r;
  };
  // ---- zero-init zone (single memset) ----
  char* zbase = ws;
  int* deg = (int*)alloc((size_t)N * 4);
  float* Uacc = (float*)alloc((size_t)G * F * 4);
  float* valg = (float*)alloc((size_t)G * 4);
  float* cntg = (float*)alloc((size_t)G * 4);
  size_t zbytes = o;
  // ---- rest ----
  int* off = (int*)alloc((size_t)(N + 1) * 4);
  int* cur = (int*)alloc((size_t)N * 4);
  float* dinv = (float*)alloc((size_t)N * 4);
  int* csr = (int*)alloc((size_t)E * 4);
  float* valn = (float*)alloc((size_t)N * 4);
  int* bsum = (int*)alloc(1024 * 4);
  float* bufA = (float*)alloc((size_t)N * F * 4);  // xs1, then h2
  float* bufB = (float*)alloc((size_t)N * F * 4);  // xs2 (=dinv*h1), then u
  (void)ws_size; (void)n_in;

  hipMemsetAsync(zbase, 0, zbytes, stream);

  const int bs = 256;
  k_count_deg<<<2048, bs, 0, stream>>>(edst, deg, E, N);
  k_bsum<<<NB, bs, 0, stream>>>(deg, bsum, N);
  k_scan_bsum<<<1, 1024, 0, stream>>>(bsum, NB);
  k_scan_fin<<<NB, bs, 0, stream>>>(deg, bsum, off, cur, dinv, N);
  k_fill<<<2048, bs, 0, stream>>>(esrc, edst, cur, csr, E, N);

  // xs1 = dinv * x
  k_scale<<<2048, bs, 0, stream>>>(x, dinv, bufA, N);

  // Persistent grid: 2048 blocks x 4 waves = 8192 waves = full residency
  // (256 CU x 8 blocks/CU at 48 VGPR). Grid-stride NPW=4 chunks keep W amortized.
  int gcnBlocks = 2048;
  // layer 1: gather xs1, GEMV W_in, write dinv*h1 (= xs2) into bufB
  k_gcn<true><<<gcnBlocks, bs, 0, stream>>>(bufA, csr, off, dinv, W_in, b_in, bufB, N);
  // layer 2: gather xs2, GEMV W1, write raw h2 into bufA
  k_gcn<false><<<gcnBlocks, bs, 0, stream>>>(bufB, csr, off, dinv, W1, b1, bufA, N);

  // fused conv_val (MFConv) + conv_policy aggregation (single gather of h2 rows)
  int aggBlocks = (N * 64 + bs - 1) / bs;  // wave per node
  k_mfpol<<<aggBlocks, bs, 0, stream>>>(bufA, csr, off, dinv, Wl, bl, Wr, valn, bufB, N);

  int poolBlocks = (N + 255) / 256;
  k_pool2<<<poolBlocks, bs, 0, stream>>>(bufB, valn, batch, Uacc, valg, cntg, N);
  k_polfin<<<(G * P + bs - 1) / bs, bs, 0, stream>>>(Uacc, valg, cntg, W_pol, b_pol, out, G);
}

// Round 7
// 244.902 us; speedup vs baseline: 1.5309x; 1.0248x over previous
//
#include <hip/hip_runtime.h>

#define F 64
#define P 32
#define MAXD 10
#define NGRP 8  // dst-range groups, mapped to XCDs via blockIdx&7 (perf hint only)

// ---------------- degree count, XCD-partitioned by dst range ----------------
__global__ void k_count_deg(const int* __restrict__ dst, int* __restrict__ deg, int E, int N) {
  int r = blockIdx.x & (NGRP - 1);           // ~XCD id == dst range id
  float scale = (float)NGRP / (float)N;      // deterministic, same in all threads
  int gblk = blockIdx.x >> 3;
  int i = gblk * blockDim.x + threadIdx.x;
  int stride = (gridDim.x >> 3) * blockDim.x;
  int E4 = E >> 2;
  const int4* d4p = (const int4*)dst;
  for (int e4 = i; e4 < E4; e4 += stride) {
    int4 d4 = d4p[e4];
    int rr;
    rr = min(NGRP - 1, (int)((float)d4.x * scale)); if (rr == r) atomicAdd(&deg[d4.x], 1);
    rr = min(NGRP - 1, (int)((float)d4.y * scale)); if (rr == r) atomicAdd(&deg[d4.y], 1);
    rr = min(NGRP - 1, (int)((float)d4.z * scale)); if (rr == r) atomicAdd(&deg[d4.z], 1);
    rr = min(NGRP - 1, (int)((float)d4.w * scale)); if (rr == r) atomicAdd(&deg[d4.w], 1);
  }
  for (int e = (E & ~3) + i; e < E; e += stride) {
    int d = dst[e];
    int rr = min(NGRP - 1, (int)((float)d * scale));
    if (rr == r) atomicAdd(&deg[d], 1);
  }
}

// ---------------- hierarchical scan: phase 1 — per-block sums (256 nodes/block) ----------------
__global__ void k_bsum(const int* __restrict__ deg, int* __restrict__ bsum, int N) {
  __shared__ int s[256];
  int t = threadIdx.x;
  int n = blockIdx.x * 256 + t;
  s[t] = (n < N) ? deg[n] : 0;
  __syncthreads();
  for (int o = 128; o > 0; o >>= 1) {
    if (t < o) s[t] += s[t + o];
    __syncthreads();
  }
  if (t == 0) bsum[blockIdx.x] = s[0];
}

// ---------------- phase 2 — single-block exclusive scan of block sums (B <= 1024) ----------------
__global__ void k_scan_bsum(int* __restrict__ bsum, int B) {
  __shared__ int s[1024];
  int t = threadIdx.x;
  int v = (t < B) ? bsum[t] : 0;
  s[t] = v;
  __syncthreads();
  for (int o = 1; o < 1024; o <<= 1) {
    int u = (t >= o) ? s[t - o] : 0;
    __syncthreads();
    s[t] += u;
    __syncthreads();
  }
  if (t < B) bsum[t] = s[t] - v;  // exclusive base per block
}

// ---------------- phase 3 — per-block local scan, write off/cur/dinv ----------------
__global__ void k_scan_fin(const int* __restrict__ deg, const int* __restrict__ bsum,
                           int* __restrict__ off, int* __restrict__ cur,
                           float* __restrict__ dinv, int N) {
  __shared__ int s[256];
  int t = threadIdx.x;
  int n = blockIdx.x * 256 + t;
  int v = (n < N) ? deg[n] : 0;
  s[t] = v;
  __syncthreads();
  for (int o = 1; o < 256; o <<= 1) {
    int u = (t >= o) ? s[t - o] : 0;
    __syncthreads();
    s[t] += u;
    __syncthreads();
  }
  if (n < N) {
    int ex = bsum[blockIdx.x] + s[t] - v;  // exclusive prefix
    off[n] = ex;
    cur[n] = ex;
    dinv[n] = rsqrtf((float)(v + 1));  // +1 self loop (GCN)
    if (n == N - 1) off[N] = ex + v;
  }
}

// ---------------- CSR fill, XCD-partitioned: csr lines for range r written by one XCD ----------
__global__ void k_fill(const int* __restrict__ src, const int* __restrict__ dst,
                       int* __restrict__ cur, int* __restrict__ csr, int E, int N) {
  int r = blockIdx.x & (NGRP - 1);
  float scale = (float)NGRP / (float)N;
  int gblk = blockIdx.x >> 3;
  int i = gblk * blockDim.x + threadIdx.x;
  int stride = (gridDim.x >> 3) * blockDim.x;
  int E4 = E >> 2;
  const int4* d4p = (const int4*)dst;
  for (int e4 = i; e4 < E4; e4 += stride) {
    int4 d4 = d4p[e4];
    int e = e4 * 4;
    int rr;
    rr = min(NGRP - 1, (int)((float)d4.x * scale));
    if (rr == r) { int pos = atomicAdd(&cur[d4.x], 1); csr[pos] = src[e]; }
    rr = min(NGRP - 1, (int)((float)d4.y * scale));
    if (rr == r) { int pos = atomicAdd(&cur[d4.y], 1); csr[pos] = src[e + 1]; }
    rr = min(NGRP - 1, (int)((float)d4.z * scale));
    if (rr == r) { int pos = atomicAdd(&cur[d4.z], 1); csr[pos] = src[e + 2]; }
    rr = min(NGRP - 1, (int)((float)d4.w * scale));
    if (rr == r) { int pos = atomicAdd(&cur[d4.w], 1); csr[pos] = src[e + 3]; }
  }
  for (int e = (E & ~3) + i; e < E; e += stride) {
    int d = dst[e];
    int rr = min(NGRP - 1, (int)((float)d * scale));
    if (rr == r) { int pos = atomicAdd(&cur[d], 1); csr[pos] = src[e]; }
  }
}

// ---------------- xs = dinv[n] * x[n]  (pre-scale for linear GCN reorder) ----------------
__global__ void k_scale(const float* __restrict__ x, const float* __restrict__ dinv,
                        float* __restrict__ xs, int N) {
  int i = blockIdx.x * blockDim.x + threadIdx.x;
  int stride = gridDim.x * blockDim.x;
  int tot = N * (F / 4);
  const float4* x4 = (const float4*)x;
  float4* xs4 = (float4*)xs;
  for (int idx = i; idx < tot; idx += stride) {
    int n = idx >> 4;  // F/4 == 16 float4 per row
    float d = dinv[n];
    float4 v = x4[idx];
    v.x *= d; v.y *= d; v.z *= d; v.w *= d;
    xs4[idx] = v;
  }
}

// readlane broadcast of float4 component: lane k>>2, component k&3 (k compile-time const)
__device__ __forceinline__ float rdl(float4 v, int k) {
  float c = (k & 3) == 0 ? v.x : (k & 3) == 1 ? v.y : (k & 3) == 2 ? v.z : v.w;
  return __int_as_float(__builtin_amdgcn_readlane(__float_as_int(c), k >> 2));
}

// ---------------- fused GCN layer: gather (4-deep MLP) + GEMV ----------------
// inner[n] = sum_{s in adj(n)} xs[s] + xs[n]   (xs pre-scaled by dinv)
// y[n,f]   = dinv[n] * <inner[n], W[:,f]> + b[f]
// WRITE_SCALED: store dinv[n]*y (next layer's pre-scaled input); else store y raw.
template <bool WRITE_SCALED>
__global__ void k_gcn(const float* __restrict__ xs, const int* __restrict__ csr,
                      const int* __restrict__ off, const float* __restrict__ dinv,
                      const float* __restrict__ W, const float* __restrict__ bias,
                      float* __restrict__ out, int N) {
  constexpr int NPW = 4;  // nodes per wave chunk (amortizes W-column load)
  int wid = (blockIdx.x * blockDim.x + threadIdx.x) >> 6;
  int lane = threadIdx.x & 63;
  int nwaves = (gridDim.x * blockDim.x) >> 6;
  int g = lane >> 4, l = lane & 15;
  float w[F];
#pragma unroll
  for (int k = 0; k < F; ++k) w[k] = W[k * F + lane];  // W column `lane`
  float bv = bias[lane];
  for (int base = wid * NPW; base < N; base += nwaves * NPW) {
#pragma unroll 1
    for (int ni = 0; ni < NPW; ++ni) {
      int n = base + ni;
      if (n >= N) break;
      int e0 = off[n], e1 = off[n + 1];
      float4 acc;
      if (g == 0)
        acc = *(const float4*)&xs[(size_t)n * F + l * 4];  // self term (group 0 only)
      else
        acc = make_float4(0.f, 0.f, 0.f, 0.f);
      for (int e = e0; e < e1; e += 64) {
        int cnt = min(64, e1 - e);
        int se = (e + lane < e1) ? csr[e + lane] : -1;
        int nfull = cnt >> 4;  // full 16-edge (4 j-step) groups: 4 loads in flight
        int j = 0;
        for (int u = 0; u < nfull; ++u, j += 4) {
          int s0 = __shfl(se, (j + 0) * 4 + g, 64);
          int s1 = __shfl(se, (j + 1) * 4 + g, 64);
          int s2 = __shfl(se, (j + 2) * 4 + g, 64);
          int s3 = __shfl(se, (j + 3) * 4 + g, 64);
          float4 v0 = *(const float4*)&xs[(size_t)s0 * F + l * 4];
          float4 v1 = *(const float4*)&xs[(size_t)s1 * F + l * 4];
          float4 v2 = *(const float4*)&xs[(size_t)s2 * F + l * 4];
          float4 v3 = *(const float4*)&xs[(size_t)s3 * F + l * 4];
          acc.x += (v0.x + v1.x) + (v2.x + v3.x);
          acc.y += (v0.y + v1.y) + (v2.y + v3.y);
          acc.z += (v0.z + v1.z) + (v2.z + v3.z);
          acc.w += (v0.w + v1.w) + (v2.w + v3.w);
        }
        int nj = (cnt + 3) >> 2;
        for (; j < nj; ++j) {
          int s = __shfl(se, j * 4 + g, 64);
          if (s >= 0) {
            float4 v = *(const float4*)&xs[(size_t)s * F + l * 4];
            acc.x += v.x; acc.y += v.y; acc.z += v.z; acc.w += v.w;
          }
        }
      }
#pragma unroll
      for (int o = 16; o < 64; o <<= 1) {  // butterfly: all lanes get full group-sum
        acc.x += __shfl_xor(acc.x, o, 64);
        acc.y += __shfl_xor(acc.y, o, 64);
        acc.z += __shfl_xor(acc.z, o, 64);
        acc.w += __shfl_xor(acc.w, o, 64);
      }
      // GEMV: every lane has inner[l*4..l*4+3]; broadcast via readlane (VALU, no LDS pipe)
      float y0 = 0.f, y1 = 0.f, y2 = 0.f, y3 = 0.f;
#pragma unroll
      for (int k = 0; k < F; k += 4) {
        y0 += rdl(acc, k) * w[k];
        y1 += rdl(acc, k + 1) * w[k + 1];
        y2 += rdl(acc, k + 2) * w[k + 2];
        y3 += rdl(acc, k + 3) * w[k + 3];
      }
      float dn = dinv[n];
      float y = dn * ((y0 + y1) + (y2 + y3)) + bv;
      if (WRITE_SCALED) y *= dn;
      out[(size_t)n * F + lane] = y;
    }
  }
}

// ---------------- fused MFConv + policy aggregation (4-deep MLP gather) ----------------
// MF:    val[n] = <sum_adj H[src], Wl[dc]> + <H[n], Wr[dc]> + bl[dc]
// pol:   u[n]   = dinv[n] * (sum_adj dinv[src]*H[src] + dinv[n]*H[n])   (W_pol deferred)
__global__ void k_mfpol(const float* __restrict__ H, const int* __restrict__ csr,
                        const int* __restrict__ off, const float* __restrict__ dinv,
                        const float* __restrict__ Wl, const float* __restrict__ bl,
                        const float* __restrict__ Wr, float* __restrict__ val,
                        float* __restrict__ u, int N) {
  int wave = (blockIdx.x * blockDim.x + threadIdx.x) >> 6;
  int lane = threadIdx.x & 63;
  if (wave >= N) return;
  int n = wave;
  int e0 = off[n], e1 = off[n + 1];
  int g = lane >> 4, l = lane & 15;
  float4 ah = make_float4(0.f, 0.f, 0.f, 0.f);
  float4 aw = make_float4(0.f, 0.f, 0.f, 0.f);
  for (int e = e0; e < e1; e += 64) {
    int cnt = min(64, e1 - e);
    int idx = e + lane;
    int se = (idx < e1) ? csr[idx] : -1;
    float dv = (se >= 0) ? dinv[se] : 0.f;
    int nfull = cnt >> 4;
    int j = 0;
    for (int uu = 0; uu < nfull; ++uu, j += 4) {
      int s0 = __shfl(se, (j + 0) * 4 + g, 64);
      int s1 = __shfl(se, (j + 1) * 4 + g, 64);
      int s2 = __shfl(se, (j + 2) * 4 + g, 64);
      int s3 = __shfl(se, (j + 3) * 4 + g, 64);
      float d0 = __shfl(dv, (j + 0) * 4 + g, 64);
      float d1 = __shfl(dv, (j + 1) * 4 + g, 64);
      float d2 = __shfl(dv, (j + 2) * 4 + g, 64);
      float d3 = __shfl(dv, (j + 3) * 4 + g, 64);
      float4 v0 = *(const float4*)&H[(size_t)s0 * F + l * 4];
      float4 v1 = *(const float4*)&H[(size_t)s1 * F + l * 4];
      float4 v2 = *(const float4*)&H[(size_t)s2 * F + l * 4];
      float4 v3 = *(const float4*)&H[(size_t)s3 * F + l * 4];
      ah.x += (v0.x + v1.x) + (v2.x + v3.x);
      ah.y += (v0.y + v1.y) + (v2.y + v3.y);
      ah.z += (v0.z + v1.z) + (v2.z + v3.z);
      ah.w += (v0.w + v1.w) + (v2.w + v3.w);
      aw.x += (d0 * v0.x + d1 * v1.x) + (d2 * v2.x + d3 * v3.x);
      aw.y += (d0 * v0.y + d1 * v1.y) + (d2 * v2.y + d3 * v3.y);
      aw.z += (d0 * v0.z + d1 * v1.z) + (d2 * v2.z + d3 * v3.z);
      aw.w += (d0 * v0.w + d1 * v1.w) + (d2 * v2.w + d3 * v3.w);
    }
    int nj = (cnt + 3) >> 2;
    for (; j < nj; ++j) {
      int sl = j * 4 + g;
      int s = __shfl(se, sl, 64);
      float dd = __shfl(dv, sl, 64);
      if (s >= 0) {
        float4 v = *(const float4*)&H[(size_t)s * F + l * 4];
        ah.x += v.x; ah.y += v.y; ah.z += v.z; ah.w += v.w;
        aw.x += dd * v.x; aw.y += dd * v.y; aw.z += dd * v.z; aw.w += dd * v.w;
      }
    }
  }
#pragma unroll
  for (int o = 16; o < 64; o <<= 1) {
    ah.x += __shfl_xor(ah.x, o, 64); ah.y += __shfl_xor(ah.y, o, 64);
    ah.z += __shfl_xor(ah.z, o, 64); ah.w += __shfl_xor(ah.w, o, 64);
    aw.x += __shfl_xor(aw.x, o, 64); aw.y += __shfl_xor(aw.y, o, 64);
    aw.z += __shfl_xor(aw.z, o, 64); aw.w += __shfl_xor(aw.w, o, 64);
  }
  int dc = min(e1 - e0, MAXD);
  float dn = dinv[n];
  float4 hn = *(const float4*)&H[(size_t)n * F + l * 4];
  float4 wl4 = *(const float4*)&Wl[dc * F + l * 4];
  float4 wr4 = *(const float4*)&Wr[dc * F + l * 4];
  float part = ah.x * wl4.x + ah.y * wl4.y + ah.z * wl4.z + ah.w * wl4.w
             + hn.x * wr4.x + hn.y * wr4.y + hn.z * wr4.z + hn.w * wr4.w;
#pragma unroll
  for (int o = 1; o < 16; o <<= 1) part += __shfl_xor(part, o, 64);
  if (lane == 0) val[n] = part + bl[dc];
  if (g == 0) {
    float4 r;
    r.x = (aw.x + dn * hn.x) * dn;
    r.y = (aw.y + dn * hn.y) * dn;
    r.z = (aw.z + dn * hn.z) * dn;
    r.w = (aw.w + dn * hn.w) * dn;
    *(float4*)&u[(size_t)n * F + l * 4] = r;
  }
}

// ---------------- pooling (batch sorted): per-block LDS accumulate of u (64f) + val + cnt ----
__global__ void k_pool2(const float* __restrict__ u, const float* __restrict__ valn,
                        const int* __restrict__ batch, float* __restrict__ Uacc,
                        float* __restrict__ valg, float* __restrict__ cntg, int N) {
  __shared__ float Ul[64 * F];
  __shared__ float Vl[64], Cl[64];
  int t = threadIdx.x;
  for (int i = t; i < 64 * F; i += 256) Ul[i] = 0.f;
  if (t < 64) { Vl[t] = 0.f; Cl[t] = 0.f; }
  __syncthreads();
  int base = blockIdx.x * 256;
  int f = t & 63, r = t >> 6;
  for (int i = r; i < 256; i += 4) {
    int n = base + i;
    if (n >= N) break;
    int g = batch[n];
    atomicAdd(&Ul[g * F + f], u[(size_t)n * F + f]);
    if (f == 0) { atomicAdd(&Vl[g], valn[n]); atomicAdd(&Cl[g], 1.f); }
  }
  __syncthreads();
  int last = min(base + 256, N) - 1;
  if (last < base) return;
  int gmin = batch[base], gmax = batch[last];
  int ng = gmax - gmin + 1;
  for (int idx = t; idx < ng * F; idx += 256) {
    int g = gmin + (idx >> 6), ff = idx & 63;
    atomicAdd(&Uacc[g * F + ff], Ul[g * F + ff]);
  }
  for (int idx = t; idx < ng; idx += 256) {
    int g = gmin + idx;
    atomicAdd(&valg[g], Vl[g]);
    atomicAdd(&cntg[g], Cl[g]);
  }
}

// ---------------- finalize: pol[g,p] = (U[g] @ W_pol)/cnt + b_pol ; copy val ----------------
__global__ void k_polfin(const float* __restrict__ Uacc, const float* __restrict__ valg,
                         const float* __restrict__ cntg, const float* __restrict__ W_pol,
                         const float* __restrict__ b_pol, float* __restrict__ out, int G) {
  int i = blockIdx.x * blockDim.x + threadIdx.x;
  if (i < G * P) {
    int g = i >> 5, p = i & 31;
    float s = 0.f;
#pragma unroll
    for (int k = 0; k < F; ++k) s += Uacc[g * F + k] * W_pol[k * P + p];
    out[i] = s / fmaxf(cntg[g], 1.f) + b_pol[p];
  }
  if (i < G) out[(size_t)G * P + i] = valg[i];
}

extern "C" void kernel_launch(void* const* d_in, const int* in_sizes, int n_in,
                              void* d_out, int out_size, void* d_ws, size_t ws_size,
                              hipStream_t stream) {
  const float* x = (const float*)d_in[0];
  const int* ei = (const int*)d_in[1];
  const int* batch = (const int*)d_in[2];
  const float* W_in = (const float*)d_in[3];
  const float* b_in = (const float*)d_in[4];
  const float* W1 = (const float*)d_in[5];
  const float* b1 = (const float*)d_in[6];
  const float* Wl = (const float*)d_in[7];
  const float* bl = (const float*)d_in[8];
  const float* Wr = (const float*)d_in[9];
  const float* W_pol = (const float*)d_in[10];
  const float* b_pol = (const float*)d_in[11];
  float* out = (float*)d_out;

  const int N = in_sizes[0] / F;
  const int E = in_sizes[1] / 2;
  const int G = out_size / (P + 1);
  const int* esrc = ei;
  const int* edst = ei + E;
  const int NB = (N + 255) / 256;  // scan blocks (196)

  char* ws = (char*)d_ws;
  size_t o = 0;
  auto alloc = [&](size_t bytes) {
    char* r = ws + o;
    o = (o + bytes + 255) & ~(size_t)255;
    return r;
  };
  // ---- zero-init zone (single memset) ----
  char* zbase = ws;
  int* deg = (int*)alloc((size_t)N * 4);
  float* Uacc = (float*)alloc((size_t)G * F * 4);
  float* valg = (float*)alloc((size_t)G * 4);
  float* cntg = (float*)alloc((size_t)G * 4);
  size_t zbytes = o;
  // ---- rest ----
  int* off = (int*)alloc((size_t)(N + 1) * 4);
  int* cur = (int*)alloc((size_t)N * 4);
  float* dinv = (float*)alloc((size_t)N * 4);
  int* csr = (int*)alloc((size_t)E * 4);
  float* valn = (float*)alloc((size_t)N * 4);
  int* bsum = (int*)alloc(1024 * 4);
  float* bufA = (float*)alloc((size_t)N * F * 4);  // xs1, then h2
  float* bufB = (float*)alloc((size_t)N * F * 4);  // xs2 (=dinv*h1), then u
  (void)ws_size; (void)n_in;

  hipMemsetAsync(zbase, 0, zbytes, stream);

  const int bs = 256;
  k_count_deg<<<2048, bs, 0, stream>>>(edst, deg, E, N);
  k_bsum<<<NB, bs, 0, stream>>>(deg, bsum, N);
  k_scan_bsum<<<1, 1024, 0, stream>>>(bsum, NB);
  k_scan_fin<<<NB, bs, 0, stream>>>(deg, bsum, off, cur, dinv, N);
  k_fill<<<2048, bs, 0, stream>>>(esrc, edst, cur, csr, E, N);

  // xs1 = dinv * x
  k_scale<<<2048, bs, 0, stream>>>(x, dinv, bufA, N);

  // Persistent grid: 2048 blocks x 4 waves; grid-stride NPW=4 chunks keep W amortized.
  int gcnBlocks = 2048;
  // layer 1: gather xs1, GEMV W_in, write dinv*h1 (= xs2) into bufB
  k_gcn<true><<<gcnBlocks, bs, 0, stream>>>(bufA, csr, off, dinv, W_in, b_in, bufB, N);
  // layer 2: gather xs2, GEMV W1, write raw h2 into bufA
  k_gcn<false><<<gcnBlocks, bs, 0, stream>>>(bufB, csr, off, dinv, W1, b1, bufA, N);

  // fused conv_val (MFConv) + conv_policy aggregation (single gather of h2 rows)
  int aggBlocks = (N * 64 + bs - 1) / bs;  // wave per node
  k_mfpol<<<aggBlocks, bs, 0, stream>>>(bufA, csr, off, dinv, Wl, bl, Wr, valn, bufB, N);

  int poolBlocks = (N + 255) / 256;
  k_pool2<<<poolBlocks, bs, 0, stream>>>(bufB, valn, batch, Uacc, valg, cntg, N);
  k_polfin<<<(G * P + bs - 1) / bs, bs, 0, stream>>>(Uacc, valg, cntg, W_pol, b_pol, out, G);
}

// Round 8
// 235.630 us; speedup vs baseline: 1.5911x; 1.0394x over previous
//
#include <hip/hip_runtime.h>

#define F 64
#define P 32
#define MAXD 10
#define NGRP 8  // dst-range groups, mapped to XCDs via blockIdx&7 (perf hint only)

// ---------------- degree count, XCD-partitioned by dst range ----------------
__global__ void k_count_deg(const int* __restrict__ dst, int* __restrict__ deg, int E, int N) {
  int r = blockIdx.x & (NGRP - 1);           // ~XCD id == dst range id
  float scale = (float)NGRP / (float)N;      // deterministic, same in all threads
  int gblk = blockIdx.x >> 3;
  int i = gblk * blockDim.x + threadIdx.x;
  int stride = (gridDim.x >> 3) * blockDim.x;
  int E4 = E >> 2;
  const int4* d4p = (const int4*)dst;
  for (int e4 = i; e4 < E4; e4 += stride) {
    int4 d4 = d4p[e4];
    int rr;
    rr = min(NGRP - 1, (int)((float)d4.x * scale)); if (rr == r) atomicAdd(&deg[d4.x], 1);
    rr = min(NGRP - 1, (int)((float)d4.y * scale)); if (rr == r) atomicAdd(&deg[d4.y], 1);
    rr = min(NGRP - 1, (int)((float)d4.z * scale)); if (rr == r) atomicAdd(&deg[d4.z], 1);
    rr = min(NGRP - 1, (int)((float)d4.w * scale)); if (rr == r) atomicAdd(&deg[d4.w], 1);
  }
  for (int e = (E & ~3) + i; e < E; e += stride) {
    int d = dst[e];
    int rr = min(NGRP - 1, (int)((float)d * scale));
    if (rr == r) atomicAdd(&deg[d], 1);
  }
}

// ---------------- hierarchical scan: phase 1 — per-block sums (256 nodes/block) ----------------
__global__ void k_bsum(const int* __restrict__ deg, int* __restrict__ bsum, int N) {
  __shared__ int s[256];
  int t = threadIdx.x;
  int n = blockIdx.x * 256 + t;
  s[t] = (n < N) ? deg[n] : 0;
  __syncthreads();
  for (int o = 128; o > 0; o >>= 1) {
    if (t < o) s[t] += s[t + o];
    __syncthreads();
  }
  if (t == 0) bsum[blockIdx.x] = s[0];
}

// ---------------- phase 2 — single-block exclusive scan of block sums (B <= 1024) ----------------
__global__ void k_scan_bsum(int* __restrict__ bsum, int B) {
  __shared__ int s[1024];
  int t = threadIdx.x;
  int v = (t < B) ? bsum[t] : 0;
  s[t] = v;
  __syncthreads();
  for (int o = 1; o < 1024; o <<= 1) {
    int u = (t >= o) ? s[t - o] : 0;
    __syncthreads();
    s[t] += u;
    __syncthreads();
  }
  if (t < B) bsum[t] = s[t] - v;  // exclusive base per block
}

// ---------------- phase 3 — per-block local scan, write off/cur/dinv ----------------
__global__ void k_scan_fin(const int* __restrict__ deg, const int* __restrict__ bsum,
                           int* __restrict__ off, int* __restrict__ cur,
                           float* __restrict__ dinv, int N) {
  __shared__ int s[256];
  int t = threadIdx.x;
  int n = blockIdx.x * 256 + t;
  int v = (n < N) ? deg[n] : 0;
  s[t] = v;
  __syncthreads();
  for (int o = 1; o < 256; o <<= 1) {
    int u = (t >= o) ? s[t - o] : 0;
    __syncthreads();
    s[t] += u;
    __syncthreads();
  }
  if (n < N) {
    int ex = bsum[blockIdx.x] + s[t] - v;  // exclusive prefix
    off[n] = ex;
    cur[n] = ex;
    dinv[n] = rsqrtf((float)(v + 1));  // +1 self loop (GCN)
    if (n == N - 1) off[N] = ex + v;
  }
}

// ---------------- CSR fill, XCD-partitioned: csr lines for range r written by one XCD ----------
__global__ void k_fill(const int* __restrict__ src, const int* __restrict__ dst,
                       int* __restrict__ cur, int* __restrict__ csr, int E, int N) {
  int r = blockIdx.x & (NGRP - 1);
  float scale = (float)NGRP / (float)N;
  int gblk = blockIdx.x >> 3;
  int i = gblk * blockDim.x + threadIdx.x;
  int stride = (gridDim.x >> 3) * blockDim.x;
  int E4 = E >> 2;
  const int4* d4p = (const int4*)dst;
  for (int e4 = i; e4 < E4; e4 += stride) {
    int4 d4 = d4p[e4];
    int e = e4 * 4;
    int rr;
    rr = min(NGRP - 1, (int)((float)d4.x * scale));
    if (rr == r) { int pos = atomicAdd(&cur[d4.x], 1); csr[pos] = src[e]; }
    rr = min(NGRP - 1, (int)((float)d4.y * scale));
    if (rr == r) { int pos = atomicAdd(&cur[d4.y], 1); csr[pos] = src[e + 1]; }
    rr = min(NGRP - 1, (int)((float)d4.z * scale));
    if (rr == r) { int pos = atomicAdd(&cur[d4.z], 1); csr[pos] = src[e + 2]; }
    rr = min(NGRP - 1, (int)((float)d4.w * scale));
    if (rr == r) { int pos = atomicAdd(&cur[d4.w], 1); csr[pos] = src[e + 3]; }
  }
  for (int e = (E & ~3) + i; e < E; e += stride) {
    int d = dst[e];
    int rr = min(NGRP - 1, (int)((float)d * scale));
    if (rr == r) { int pos = atomicAdd(&cur[d], 1); csr[pos] = src[e]; }
  }
}

// ---------------- xs = dinv[n] * x[n]  (pre-scale for linear GCN reorder) ----------------
__global__ void k_scale(const float* __restrict__ x, const float* __restrict__ dinv,
                        float* __restrict__ xs, int N) {
  int i = blockIdx.x * blockDim.x + threadIdx.x;
  int stride = gridDim.x * blockDim.x;
  int tot = N * (F / 4);
  const float4* x4 = (const float4*)x;
  float4* xs4 = (float4*)xs;
  for (int idx = i; idx < tot; idx += stride) {
    int n = idx >> 4;  // F/4 == 16 float4 per row
    float d = dinv[n];
    float4 v = x4[idx];
    v.x *= d; v.y *= d; v.z *= d; v.w *= d;
    xs4[idx] = v;
  }
}

// readlane: compile-time source lane (after unroll)
__device__ __forceinline__ float rdlane(float v, int srclane) {
  return __int_as_float(__builtin_amdgcn_readlane(__float_as_int(v), srclane));
}

// ---------------- fused GCN layer: node-per-16-lane-group gather + GEMV ----------------
// 4 nodes per wave, one per group -> 4 independent latency chains, no cross-group reduce.
// inner[n] = sum_{s in adj(n)} xs[s] + xs[n]   (xs pre-scaled by dinv)
// y[n,f]   = dinv[n] * <inner[n], W[:,f]> + b[f];  WRITE_SCALED stores dinv*y.
template <bool WRITE_SCALED>
__global__ void k_gcn(const float* __restrict__ xs, const int* __restrict__ csr,
                      const int* __restrict__ off, const float* __restrict__ dinv,
                      const float* __restrict__ W, const float* __restrict__ bias,
                      float* __restrict__ out, int N) {
  int wid = (blockIdx.x * blockDim.x + threadIdx.x) >> 6;
  int lane = threadIdx.x & 63;
  int nwaves = (gridDim.x * blockDim.x) >> 6;
  int g = lane >> 4, l = lane & 15;
  float w[F];
#pragma unroll
  for (int k = 0; k < F; ++k) w[k] = W[k * F + lane];  // W column `lane`
  float bv = bias[lane];
  for (int base = wid * 4; base < N; base += nwaves * 4) {
    int n = min(base + g, N - 1);  // group's node (clamped; stores guarded below)
    int e0 = off[n], e1 = off[n + 1];
    float dnode = dinv[n];
    // self term: whole group loads node's own row (lane l -> feats l*4..l*4+3)
    float4 acc = *(const float4*)&xs[(size_t)n * F + l * 4];
    for (int win = e0; win < e1; win += 16) {
      int m = min(16, e1 - win);
      int ce = (win + l < e1) ? csr[win + l] : 0;  // 16 contiguous edges, coalesced
      int j = 0;
      for (; j + 4 <= m; j += 4) {  // 4 rows in flight per group (16/wave)
        int s0 = __shfl(ce, g * 16 + j + 0, 64);
        int s1 = __shfl(ce, g * 16 + j + 1, 64);
        int s2 = __shfl(ce, g * 16 + j + 2, 64);
        int s3 = __shfl(ce, g * 16 + j + 3, 64);
        float4 v0 = *(const float4*)&xs[(size_t)s0 * F + l * 4];
        float4 v1 = *(const float4*)&xs[(size_t)s1 * F + l * 4];
        float4 v2 = *(const float4*)&xs[(size_t)s2 * F + l * 4];
        float4 v3 = *(const float4*)&xs[(size_t)s3 * F + l * 4];
        acc.x += (v0.x + v1.x) + (v2.x + v3.x);
        acc.y += (v0.y + v1.y) + (v2.y + v3.y);
        acc.z += (v0.z + v1.z) + (v2.z + v3.z);
        acc.w += (v0.w + v1.w) + (v2.w + v3.w);
      }
      for (; j < m; ++j) {
        int s = __shfl(ce, g * 16 + j, 64);
        float4 v = *(const float4*)&xs[(size_t)s * F + l * 4];
        acc.x += v.x; acc.y += v.y; acc.z += v.z; acc.w += v.w;
      }
    }
    // GEMV per node (gg compile-time after unroll -> readlane legal); no butterfly needed.
#pragma unroll
    for (int gg = 0; gg < 4; ++gg) {
      float y0 = 0.f, y1 = 0.f, y2 = 0.f, y3 = 0.f;
#pragma unroll
      for (int k = 0; k < F; k += 4) {
        y0 += rdlane(acc.x, gg * 16 + (k >> 2)) * w[k + 0];
        y1 += rdlane(acc.y, gg * 16 + (k >> 2)) * w[k + 1];
        y2 += rdlane(acc.z, gg * 16 + (k >> 2)) * w[k + 2];
        y3 += rdlane(acc.w, gg * 16 + (k >> 2)) * w[k + 3];
      }
      float dd = rdlane(dnode, gg * 16);
      float y = dd * ((y0 + y1) + (y2 + y3)) + bv;
      if (WRITE_SCALED) y *= dd;
      int nn = base + gg;
      if (nn < N) out[(size_t)nn * F + lane] = y;
    }
  }
}

// ---------------- fused MFConv + policy aggregation, node-per-group ----------------
// MF:    val[n] = <sum_adj H[src], Wl[dc]> + <H[n], Wr[dc]> + bl[dc]
// pol:   u[n]   = dinv[n] * (sum_adj dinv[src]*H[src] + dinv[n]*H[n])   (W_pol deferred)
__global__ void k_mfpol(const float* __restrict__ H, const int* __restrict__ csr,
                        const int* __restrict__ off, const float* __restrict__ dinv,
                        const float* __restrict__ Wl, const float* __restrict__ bl,
                        const float* __restrict__ Wr, float* __restrict__ val,
                        float* __restrict__ u, int N) {
  int wid = (blockIdx.x * blockDim.x + threadIdx.x) >> 6;
  int lane = threadIdx.x & 63;
  int nwaves = (gridDim.x * blockDim.x) >> 6;
  int g = lane >> 4, l = lane & 15;
  for (int base = wid * 4; base < N; base += nwaves * 4) {
    bool valid = (base + g) < N;
    int n = min(base + g, N - 1);
    int e0 = off[n], e1 = off[n + 1];
    float dn = dinv[n];
    float4 ah = make_float4(0.f, 0.f, 0.f, 0.f);
    float4 aw = make_float4(0.f, 0.f, 0.f, 0.f);
    for (int win = e0; win < e1; win += 16) {
      int m = min(16, e1 - win);
      bool p = (win + l < e1);
      int ce = p ? csr[win + l] : 0;
      float cd = p ? dinv[ce] : 0.f;
      int j = 0;
      for (; j + 4 <= m; j += 4) {
        int s0 = __shfl(ce, g * 16 + j + 0, 64);
        int s1 = __shfl(ce, g * 16 + j + 1, 64);
        int s2 = __shfl(ce, g * 16 + j + 2, 64);
        int s3 = __shfl(ce, g * 16 + j + 3, 64);
        float d0 = __shfl(cd, g * 16 + j + 0, 64);
        float d1 = __shfl(cd, g * 16 + j + 1, 64);
        float d2 = __shfl(cd, g * 16 + j + 2, 64);
        float d3 = __shfl(cd, g * 16 + j + 3, 64);
        float4 v0 = *(const float4*)&H[(size_t)s0 * F + l * 4];
        float4 v1 = *(const float4*)&H[(size_t)s1 * F + l * 4];
        float4 v2 = *(const float4*)&H[(size_t)s2 * F + l * 4];
        float4 v3 = *(const float4*)&H[(size_t)s3 * F + l * 4];
        ah.x += (v0.x + v1.x) + (v2.x + v3.x);
        ah.y += (v0.y + v1.y) + (v2.y + v3.y);
        ah.z += (v0.z + v1.z) + (v2.z + v3.z);
        ah.w += (v0.w + v1.w) + (v2.w + v3.w);
        aw.x += (d0 * v0.x + d1 * v1.x) + (d2 * v2.x + d3 * v3.x);
        aw.y += (d0 * v0.y + d1 * v1.y) + (d2 * v2.y + d3 * v3.y);
        aw.z += (d0 * v0.z + d1 * v1.z) + (d2 * v2.z + d3 * v3.z);
        aw.w += (d0 * v0.w + d1 * v1.w) + (d2 * v2.w + d3 * v3.w);
      }
      for (; j < m; ++j) {
        int s = __shfl(ce, g * 16 + j, 64);
        float dd = __shfl(cd, g * 16 + j, 64);
        float4 v = *(const float4*)&H[(size_t)s * F + l * 4];
        ah.x += v.x; ah.y += v.y; ah.z += v.z; ah.w += v.w;
        aw.x += dd * v.x; aw.y += dd * v.y; aw.z += dd * v.z; aw.w += dd * v.w;
      }
    }
    int dc = min(e1 - e0, MAXD);
    float4 hn = *(const float4*)&H[(size_t)n * F + l * 4];
    float4 wl4 = *(const float4*)&Wl[dc * F + l * 4];
    float4 wr4 = *(const float4*)&Wr[dc * F + l * 4];
    float part = ah.x * wl4.x + ah.y * wl4.y + ah.z * wl4.z + ah.w * wl4.w
               + hn.x * wr4.x + hn.y * wr4.y + hn.z * wr4.z + hn.w * wr4.w;
#pragma unroll
    for (int o = 1; o < 16; o <<= 1) part += __shfl_xor(part, o, 64);  // in-group reduce
    if (l == 0 && valid) val[n] = part + bl[dc];
    if (valid) {
      float4 r;
      r.x = (aw.x + dn * hn.x) * dn;
      r.y = (aw.y + dn * hn.y) * dn;
      r.z = (aw.z + dn * hn.z) * dn;
      r.w = (aw.w + dn * hn.w) * dn;
      *(float4*)&u[(size_t)n * F + l * 4] = r;
    }
  }
}

// ---------------- pooling (batch sorted): per-block LDS accumulate of u (64f) + val + cnt ----
__global__ void k_pool2(const float* __restrict__ u, const float* __restrict__ valn,
                        const int* __restrict__ batch, float* __restrict__ Uacc,
                        float* __restrict__ valg, float* __restrict__ cntg, int N) {
  __shared__ float Ul[64 * F];
  __shared__ float Vl[64], Cl[64];
  int t = threadIdx.x;
  for (int i = t; i < 64 * F; i += 256) Ul[i] = 0.f;
  if (t < 64) { Vl[t] = 0.f; Cl[t] = 0.f; }
  __syncthreads();
  int base = blockIdx.x * 256;
  int f = t & 63, r = t >> 6;
  for (int i = r; i < 256; i += 4) {
    int n = base + i;
    if (n >= N) break;
    int g = batch[n];
    atomicAdd(&Ul[g * F + f], u[(size_t)n * F + f]);
    if (f == 0) { atomicAdd(&Vl[g], valn[n]); atomicAdd(&Cl[g], 1.f); }
  }
  __syncthreads();
  int last = min(base + 256, N) - 1;
  if (last < base) return;
  int gmin = batch[base], gmax = batch[last];
  int ng = gmax - gmin + 1;
  for (int idx = t; idx < ng * F; idx += 256) {
    int g = gmin + (idx >> 6), ff = idx & 63;
    atomicAdd(&Uacc[g * F + ff], Ul[g * F + ff]);
  }
  for (int idx = t; idx < ng; idx += 256) {
    int g = gmin + idx;
    atomicAdd(&valg[g], Vl[g]);
    atomicAdd(&cntg[g], Cl[g]);
  }
}

// ---------------- finalize: pol[g,p] = (U[g] @ W_pol)/cnt + b_pol ; copy val ----------------
__global__ void k_polfin(const float* __restrict__ Uacc, const float* __restrict__ valg,
                         const float* __restrict__ cntg, const float* __restrict__ W_pol,
                         const float* __restrict__ b_pol, float* __restrict__ out, int G) {
  int i = blockIdx.x * blockDim.x + threadIdx.x;
  if (i < G * P) {
    int g = i >> 5, p = i & 31;
    float s = 0.f;
#pragma unroll
    for (int k = 0; k < F; ++k) s += Uacc[g * F + k] * W_pol[k * P + p];
    out[i] = s / fmaxf(cntg[g], 1.f) + b_pol[p];
  }
  if (i < G) out[(size_t)G * P + i] = valg[i];
}

extern "C" void kernel_launch(void* const* d_in, const int* in_sizes, int n_in,
                              void* d_out, int out_size, void* d_ws, size_t ws_size,
                              hipStream_t stream) {
  const float* x = (const float*)d_in[0];
  const int* ei = (const int*)d_in[1];
  const int* batch = (const int*)d_in[2];
  const float* W_in = (const float*)d_in[3];
  const float* b_in = (const float*)d_in[4];
  const float* W1 = (const float*)d_in[5];
  const float* b1 = (const float*)d_in[6];
  const float* Wl = (const float*)d_in[7];
  const float* bl = (const float*)d_in[8];
  const float* Wr = (const float*)d_in[9];
  const float* W_pol = (const float*)d_in[10];
  const float* b_pol = (const float*)d_in[11];
  float* out = (float*)d_out;

  const int N = in_sizes[0] / F;
  const int E = in_sizes[1] / 2;
  const int G = out_size / (P + 1);
  const int* esrc = ei;
  const int* edst = ei + E;
  const int NB = (N + 255) / 256;  // scan blocks (196)

  char* ws = (char*)d_ws;
  size_t o = 0;
  auto alloc = [&](size_t bytes) {
    char* r = ws + o;
    o = (o + bytes + 255) & ~(size_t)255;
    return r;
  };
  // ---- zero-init zone (single memset) ----
  char* zbase = ws;
  int* deg = (int*)alloc((size_t)N * 4);
  float* Uacc = (float*)alloc((size_t)G * F * 4);
  float* valg = (float*)alloc((size_t)G * 4);
  float* cntg = (float*)alloc((size_t)G * 4);
  size_t zbytes = o;
  // ---- rest ----
  int* off = (int*)alloc((size_t)(N + 1) * 4);
  int* cur = (int*)alloc((size_t)N * 4);
  float* dinv = (float*)alloc((size_t)N * 4);
  int* csr = (int*)alloc((size_t)E * 4);
  float* valn = (float*)alloc((size_t)N * 4);
  int* bsum = (int*)alloc(1024 * 4);
  float* bufA = (float*)alloc((size_t)N * F * 4);  // xs1, then h2
  float* bufB = (float*)alloc((size_t)N * F * 4);  // xs2 (=dinv*h1), then u
  (void)ws_size; (void)n_in;

  hipMemsetAsync(zbase, 0, zbytes, stream);

  const int bs = 256;
  k_count_deg<<<2048, bs, 0, stream>>>(edst, deg, E, N);
  k_bsum<<<NB, bs, 0, stream>>>(deg, bsum, N);
  k_scan_bsum<<<1, 1024, 0, stream>>>(bsum, NB);
  k_scan_fin<<<NB, bs, 0, stream>>>(deg, bsum, off, cur, dinv, N);
  k_fill<<<2048, bs, 0, stream>>>(esrc, edst, cur, csr, E, N);

  // xs1 = dinv * x
  k_scale<<<2048, bs, 0, stream>>>(x, dinv, bufA, N);

  // 16 nodes per block (4 waves x 4 groups): exact single-pass grid
  int gBlocks = (N + 15) / 16;
  // layer 1: gather xs1, GEMV W_in, write dinv*h1 (= xs2) into bufB
  k_gcn<true><<<gBlocks, bs, 0, stream>>>(bufA, csr, off, dinv, W_in, b_in, bufB, N);
  // layer 2: gather xs2, GEMV W1, write raw h2 into bufA
  k_gcn<false><<<gBlocks, bs, 0, stream>>>(bufB, csr, off, dinv, W1, b1, bufA, N);

  // fused conv_val (MFConv) + conv_policy aggregation (single gather of h2 rows)
  k_mfpol<<<gBlocks, bs, 0, stream>>>(bufA, csr, off, dinv, Wl, bl, Wr, valn, bufB, N);

  int poolBlocks = (N + 255) / 256;
  k_pool2<<<poolBlocks, bs, 0, stream>>>(bufB, valn, batch, Uacc, valg, cntg, N);
  k_polfin<<<(G * P + bs - 1) / bs, bs, 0, stream>>>(Uacc, valg, cntg, W_pol, b_pol, out, G);
}

// Round 9
// 235.393 us; speedup vs baseline: 1.5927x; 1.0010x over previous
//
#include <hip/hip_runtime.h>

#define F 64
#define P 32
#define MAXD 10
#define NGRP 8  // dst-range groups, mapped to XCDs via blockIdx&7 (perf hint only)

// ---------------- zero-init (replaces rocclr fillBuffer: ~43us overhead -> ~3us) ----------------
__global__ void k_zero(float4* __restrict__ p, int n4) {
  int i = blockIdx.x * blockDim.x + threadIdx.x;
  int stride = gridDim.x * blockDim.x;
  float4 z = make_float4(0.f, 0.f, 0.f, 0.f);
  for (int idx = i; idx < n4; idx += stride) p[idx] = z;
}

// ---------------- degree count, XCD-partitioned by dst range ----------------
__global__ void k_count_deg(const int* __restrict__ dst, int* __restrict__ deg, int E, int N) {
  int r = blockIdx.x & (NGRP - 1);           // ~XCD id == dst range id
  float scale = (float)NGRP / (float)N;      // deterministic, same in all threads
  int gblk = blockIdx.x >> 3;
  int i = gblk * blockDim.x + threadIdx.x;
  int stride = (gridDim.x >> 3) * blockDim.x;
  int E4 = E >> 2;
  const int4* d4p = (const int4*)dst;
  for (int e4 = i; e4 < E4; e4 += stride) {
    int4 d4 = d4p[e4];
    int rr;
    rr = min(NGRP - 1, (int)((float)d4.x * scale)); if (rr == r) atomicAdd(&deg[d4.x], 1);
    rr = min(NGRP - 1, (int)((float)d4.y * scale)); if (rr == r) atomicAdd(&deg[d4.y], 1);
    rr = min(NGRP - 1, (int)((float)d4.z * scale)); if (rr == r) atomicAdd(&deg[d4.z], 1);
    rr = min(NGRP - 1, (int)((float)d4.w * scale)); if (rr == r) atomicAdd(&deg[d4.w], 1);
  }
  for (int e = (E & ~3) + i; e < E; e += stride) {
    int d = dst[e];
    int rr = min(NGRP - 1, (int)((float)d * scale));
    if (rr == r) atomicAdd(&deg[d], 1);
  }
}

// ---------------- hierarchical scan: phase 1 — per-block sums (256 nodes/block) ----------------
__global__ void k_bsum(const int* __restrict__ deg, int* __restrict__ bsum, int N) {
  __shared__ int s[256];
  int t = threadIdx.x;
  int n = blockIdx.x * 256 + t;
  s[t] = (n < N) ? deg[n] : 0;
  __syncthreads();
  for (int o = 128; o > 0; o >>= 1) {
    if (t < o) s[t] += s[t + o];
    __syncthreads();
  }
  if (t == 0) bsum[blockIdx.x] = s[0];
}

// ---------------- phase 2 — single-block exclusive scan of block sums (B <= 1024) ----------------
__global__ void k_scan_bsum(int* __restrict__ bsum, int B) {
  __shared__ int s[1024];
  int t = threadIdx.x;
  int v = (t < B) ? bsum[t] : 0;
  s[t] = v;
  __syncthreads();
  for (int o = 1; o < 1024; o <<= 1) {
    int u = (t >= o) ? s[t - o] : 0;
    __syncthreads();
    s[t] += u;
    __syncthreads();
  }
  if (t < B) bsum[t] = s[t] - v;  // exclusive base per block
}

// ---------------- phase 3 — per-block local scan, write off/cur/dinv ----------------
__global__ void k_scan_fin(const int* __restrict__ deg, const int* __restrict__ bsum,
                           int* __restrict__ off, int* __restrict__ cur,
                           float* __restrict__ dinv, int N) {
  __shared__ int s[256];
  int t = threadIdx.x;
  int n = blockIdx.x * 256 + t;
  int v = (n < N) ? deg[n] : 0;
  s[t] = v;
  __syncthreads();
  for (int o = 1; o < 256; o <<= 1) {
    int u = (t >= o) ? s[t - o] : 0;
    __syncthreads();
    s[t] += u;
    __syncthreads();
  }
  if (n < N) {
    int ex = bsum[blockIdx.x] + s[t] - v;  // exclusive prefix
    off[n] = ex;
    cur[n] = ex;
    dinv[n] = rsqrtf((float)(v + 1));  // +1 self loop (GCN)
    if (n == N - 1) off[N] = ex + v;
  }
}

// ---------------- CSR fill, XCD-partitioned: csr lines for range r written by one XCD ----------
__global__ void k_fill(const int* __restrict__ src, const int* __restrict__ dst,
                       int* __restrict__ cur, int* __restrict__ csr, int E, int N) {
  int r = blockIdx.x & (NGRP - 1);
  float scale = (float)NGRP / (float)N;
  int gblk = blockIdx.x >> 3;
  int i = gblk * blockDim.x + threadIdx.x;
  int stride = (gridDim.x >> 3) * blockDim.x;
  int E4 = E >> 2;
  const int4* d4p = (const int4*)dst;
  for (int e4 = i; e4 < E4; e4 += stride) {
    int4 d4 = d4p[e4];
    int e = e4 * 4;
    int rr;
    rr = min(NGRP - 1, (int)((float)d4.x * scale));
    if (rr == r) { int pos = atomicAdd(&cur[d4.x], 1); csr[pos] = src[e]; }
    rr = min(NGRP - 1, (int)((float)d4.y * scale));
    if (rr == r) { int pos = atomicAdd(&cur[d4.y], 1); csr[pos] = src[e + 1]; }
    rr = min(NGRP - 1, (int)((float)d4.z * scale));
    if (rr == r) { int pos = atomicAdd(&cur[d4.z], 1); csr[pos] = src[e + 2]; }
    rr = min(NGRP - 1, (int)((float)d4.w * scale));
    if (rr == r) { int pos = atomicAdd(&cur[d4.w], 1); csr[pos] = src[e + 3]; }
  }
  for (int e = (E & ~3) + i; e < E; e += stride) {
    int d = dst[e];
    int rr = min(NGRP - 1, (int)((float)d * scale));
    if (rr == r) { int pos = atomicAdd(&cur[d], 1); csr[pos] = src[e]; }
  }
}

// ---------------- xs = dinv[n] * x[n]  (pre-scale for linear GCN reorder) ----------------
__global__ void k_scale(const float* __restrict__ x, const float* __restrict__ dinv,
                        float* __restrict__ xs, int N) {
  int i = blockIdx.x * blockDim.x + threadIdx.x;
  int stride = gridDim.x * blockDim.x;
  int tot = N * (F / 4);
  const float4* x4 = (const float4*)x;
  float4* xs4 = (float4*)xs;
  for (int idx = i; idx < tot; idx += stride) {
    int n = idx >> 4;  // F/4 == 16 float4 per row
    float d = dinv[n];
    float4 v = x4[idx];
    v.x *= d; v.y *= d; v.z *= d; v.w *= d;
    xs4[idx] = v;
  }
}

// readlane: compile-time source lane (after unroll)
__device__ __forceinline__ float rdlane(float v, int srclane) {
  return __int_as_float(__builtin_amdgcn_readlane(__float_as_int(v), srclane));
}

// ---------------- fused GCN layer: node-per-16-lane-group gather + GEMV ----------------
// 4 nodes per wave, one per group -> 4 independent latency chains, no cross-group reduce.
// inner[n] = sum_{s in adj(n)} xs[s] + xs[n]   (xs pre-scaled by dinv)
// y[n,f]   = dinv[n] * <inner[n], W[:,f]> + b[f];  WRITE_SCALED stores dinv*y.
template <bool WRITE_SCALED>
__global__ void k_gcn(const float* __restrict__ xs, const int* __restrict__ csr,
                      const int* __restrict__ off, const float* __restrict__ dinv,
                      const float* __restrict__ W, const float* __restrict__ bias,
                      float* __restrict__ out, int N) {
  int wid = (blockIdx.x * blockDim.x + threadIdx.x) >> 6;
  int lane = threadIdx.x & 63;
  int nwaves = (gridDim.x * blockDim.x) >> 6;
  int g = lane >> 4, l = lane & 15;
  float w[F];
#pragma unroll
  for (int k = 0; k < F; ++k) w[k] = W[k * F + lane];  // W column `lane`
  float bv = bias[lane];
  for (int base = wid * 4; base < N; base += nwaves * 4) {
    int n = min(base + g, N - 1);  // group's node (clamped; stores guarded below)
    int e0 = off[n], e1 = off[n + 1];
    float dnode = dinv[n];
    // self term: whole group loads node's own row (lane l -> feats l*4..l*4+3)
    float4 acc = *(const float4*)&xs[(size_t)n * F + l * 4];
    for (int win = e0; win < e1; win += 16) {
      int m = min(16, e1 - win);
      int ce = (win + l < e1) ? csr[win + l] : 0;  // 16 contiguous edges, coalesced
      int j = 0;
      for (; j + 4 <= m; j += 4) {  // 4 rows in flight per group (16/wave)
        int s0 = __shfl(ce, g * 16 + j + 0, 64);
        int s1 = __shfl(ce, g * 16 + j + 1, 64);
        int s2 = __shfl(ce, g * 16 + j + 2, 64);
        int s3 = __shfl(ce, g * 16 + j + 3, 64);
        float4 v0 = *(const float4*)&xs[(size_t)s0 * F + l * 4];
        float4 v1 = *(const float4*)&xs[(size_t)s1 * F + l * 4];
        float4 v2 = *(const float4*)&xs[(size_t)s2 * F + l * 4];
        float4 v3 = *(const float4*)&xs[(size_t)s3 * F + l * 4];
        acc.x += (v0.x + v1.x) + (v2.x + v3.x);
        acc.y += (v0.y + v1.y) + (v2.y + v3.y);
        acc.z += (v0.z + v1.z) + (v2.z + v3.z);
        acc.w += (v0.w + v1.w) + (v2.w + v3.w);
      }
      for (; j < m; ++j) {
        int s = __shfl(ce, g * 16 + j, 64);
        float4 v = *(const float4*)&xs[(size_t)s * F + l * 4];
        acc.x += v.x; acc.y += v.y; acc.z += v.z; acc.w += v.w;
      }
    }
    // GEMV per node (gg compile-time after unroll -> readlane legal); no butterfly needed.
#pragma unroll
    for (int gg = 0; gg < 4; ++gg) {
      float y0 = 0.f, y1 = 0.f, y2 = 0.f, y3 = 0.f;
#pragma unroll
      for (int k = 0; k < F; k += 4) {
        y0 += rdlane(acc.x, gg * 16 + (k >> 2)) * w[k + 0];
        y1 += rdlane(acc.y, gg * 16 + (k >> 2)) * w[k + 1];
        y2 += rdlane(acc.z, gg * 16 + (k >> 2)) * w[k + 2];
        y3 += rdlane(acc.w, gg * 16 + (k >> 2)) * w[k + 3];
      }
      float dd = rdlane(dnode, gg * 16);
      float y = dd * ((y0 + y1) + (y2 + y3)) + bv;
      if (WRITE_SCALED) y *= dd;
      int nn = base + gg;
      if (nn < N) out[(size_t)nn * F + lane] = y;
    }
  }
}

// ---------------- fused MFConv + policy aggregation, node-per-group ----------------
// MF:    val[n] = <sum_adj H[src], Wl[dc]> + <H[n], Wr[dc]> + bl[dc]
// pol:   u[n]   = dinv[n] * (sum_adj dinv[src]*H[src] + dinv[n]*H[n])   (W_pol deferred)
__global__ void k_mfpol(const float* __restrict__ H, const int* __restrict__ csr,
                        const int* __restrict__ off, const float* __restrict__ dinv,
                        const float* __restrict__ Wl, const float* __restrict__ bl,
                        const float* __restrict__ Wr, float* __restrict__ val,
                        float* __restrict__ u, int N) {
  int wid = (blockIdx.x * blockDim.x + threadIdx.x) >> 6;
  int lane = threadIdx.x & 63;
  int nwaves = (gridDim.x * blockDim.x) >> 6;
  int g = lane >> 4, l = lane & 15;
  for (int base = wid * 4; base < N; base += nwaves * 4) {
    bool valid = (base + g) < N;
    int n = min(base + g, N - 1);
    int e0 = off[n], e1 = off[n + 1];
    float dn = dinv[n];
    float4 ah = make_float4(0.f, 0.f, 0.f, 0.f);
    float4 aw = make_float4(0.f, 0.f, 0.f, 0.f);
    for (int win = e0; win < e1; win += 16) {
      int m = min(16, e1 - win);
      bool p = (win + l < e1);
      int ce = p ? csr[win + l] : 0;
      float cd = p ? dinv[ce] : 0.f;
      int j = 0;
      for (; j + 4 <= m; j += 4) {
        int s0 = __shfl(ce, g * 16 + j + 0, 64);
        int s1 = __shfl(ce, g * 16 + j + 1, 64);
        int s2 = __shfl(ce, g * 16 + j + 2, 64);
        int s3 = __shfl(ce, g * 16 + j + 3, 64);
        float d0 = __shfl(cd, g * 16 + j + 0, 64);
        float d1 = __shfl(cd, g * 16 + j + 1, 64);
        float d2 = __shfl(cd, g * 16 + j + 2, 64);
        float d3 = __shfl(cd, g * 16 + j + 3, 64);
        float4 v0 = *(const float4*)&H[(size_t)s0 * F + l * 4];
        float4 v1 = *(const float4*)&H[(size_t)s1 * F + l * 4];
        float4 v2 = *(const float4*)&H[(size_t)s2 * F + l * 4];
        float4 v3 = *(const float4*)&H[(size_t)s3 * F + l * 4];
        ah.x += (v0.x + v1.x) + (v2.x + v3.x);
        ah.y += (v0.y + v1.y) + (v2.y + v3.y);
        ah.z += (v0.z + v1.z) + (v2.z + v3.z);
        ah.w += (v0.w + v1.w) + (v2.w + v3.w);
        aw.x += (d0 * v0.x + d1 * v1.x) + (d2 * v2.x + d3 * v3.x);
        aw.y += (d0 * v0.y + d1 * v1.y) + (d2 * v2.y + d3 * v3.y);
        aw.z += (d0 * v0.z + d1 * v1.z) + (d2 * v2.z + d3 * v3.z);
        aw.w += (d0 * v0.w + d1 * v1.w) + (d2 * v2.w + d3 * v3.w);
      }
      for (; j < m; ++j) {
        int s = __shfl(ce, g * 16 + j, 64);
        float dd = __shfl(cd, g * 16 + j, 64);
        float4 v = *(const float4*)&H[(size_t)s * F + l * 4];
        ah.x += v.x; ah.y += v.y; ah.z += v.z; ah.w += v.w;
        aw.x += dd * v.x; aw.y += dd * v.y; aw.z += dd * v.z; aw.w += dd * v.w;
      }
    }
    int dc = min(e1 - e0, MAXD);
    float4 hn = *(const float4*)&H[(size_t)n * F + l * 4];
    float4 wl4 = *(const float4*)&Wl[dc * F + l * 4];
    float4 wr4 = *(const float4*)&Wr[dc * F + l * 4];
    float part = ah.x * wl4.x + ah.y * wl4.y + ah.z * wl4.z + ah.w * wl4.w
               + hn.x * wr4.x + hn.y * wr4.y + hn.z * wr4.z + hn.w * wr4.w;
#pragma unroll
    for (int o = 1; o < 16; o <<= 1) part += __shfl_xor(part, o, 64);  // in-group reduce
    if (l == 0 && valid) val[n] = part + bl[dc];
    if (valid) {
      float4 r;
      r.x = (aw.x + dn * hn.x) * dn;
      r.y = (aw.y + dn * hn.y) * dn;
      r.z = (aw.z + dn * hn.z) * dn;
      r.w = (aw.w + dn * hn.w) * dn;
      *(float4*)&u[(size_t)n * F + l * 4] = r;
    }
  }
}

// ---------------- pooling (batch sorted): per-block LDS accumulate of u (64f) + val + cnt ----
__global__ void k_pool2(const float* __restrict__ u, const float* __restrict__ valn,
                        const int* __restrict__ batch, float* __restrict__ Uacc,
                        float* __restrict__ valg, float* __restrict__ cntg, int N) {
  __shared__ float Ul[64 * F];
  __shared__ float Vl[64], Cl[64];
  int t = threadIdx.x;
  for (int i = t; i < 64 * F; i += 256) Ul[i] = 0.f;
  if (t < 64) { Vl[t] = 0.f; Cl[t] = 0.f; }
  __syncthreads();
  int base = blockIdx.x * 256;
  int f = t & 63, r = t >> 6;
  for (int i = r; i < 256; i += 4) {
    int n = base + i;
    if (n >= N) break;
    int g = batch[n];
    atomicAdd(&Ul[g * F + f], u[(size_t)n * F + f]);
    if (f == 0) { atomicAdd(&Vl[g], valn[n]); atomicAdd(&Cl[g], 1.f); }
  }
  __syncthreads();
  int last = min(base + 256, N) - 1;
  if (last < base) return;
  int gmin = batch[base], gmax = batch[last];
  int ng = gmax - gmin + 1;
  for (int idx = t; idx < ng * F; idx += 256) {
    int g = gmin + (idx >> 6), ff = idx & 63;
    atomicAdd(&Uacc[g * F + ff], Ul[g * F + ff]);
  }
  for (int idx = t; idx < ng; idx += 256) {
    int g = gmin + idx;
    atomicAdd(&valg[g], Vl[g]);
    atomicAdd(&cntg[g], Cl[g]);
  }
}

// ---------------- finalize: pol[g,p] = (U[g] @ W_pol)/cnt + b_pol ; copy val ----------------
__global__ void k_polfin(const float* __restrict__ Uacc, const float* __restrict__ valg,
                         const float* __restrict__ cntg, const float* __restrict__ W_pol,
                         const float* __restrict__ b_pol, float* __restrict__ out, int G) {
  int i = blockIdx.x * blockDim.x + threadIdx.x;
  if (i < G * P) {
    int g = i >> 5, p = i & 31;
    float s = 0.f;
#pragma unroll
    for (int k = 0; k < F; ++k) s += Uacc[g * F + k] * W_pol[k * P + p];
    out[i] = s / fmaxf(cntg[g], 1.f) + b_pol[p];
  }
  if (i < G) out[(size_t)G * P + i] = valg[i];
}

extern "C" void kernel_launch(void* const* d_in, const int* in_sizes, int n_in,
                              void* d_out, int out_size, void* d_ws, size_t ws_size,
                              hipStream_t stream) {
  const float* x = (const float*)d_in[0];
  const int* ei = (const int*)d_in[1];
  const int* batch = (const int*)d_in[2];
  const float* W_in = (const float*)d_in[3];
  const float* b_in = (const float*)d_in[4];
  const float* W1 = (const float*)d_in[5];
  const float* b1 = (const float*)d_in[6];
  const float* Wl = (const float*)d_in[7];
  const float* bl = (const float*)d_in[8];
  const float* Wr = (const float*)d_in[9];
  const float* W_pol = (const float*)d_in[10];
  const float* b_pol = (const float*)d_in[11];
  float* out = (float*)d_out;

  const int N = in_sizes[0] / F;
  const int E = in_sizes[1] / 2;
  const int G = out_size / (P + 1);
  const int* esrc = ei;
  const int* edst = ei + E;
  const int NB = (N + 255) / 256;  // scan blocks (196)

  char* ws = (char*)d_ws;
  size_t o = 0;
  auto alloc = [&](size_t bytes) {
    char* r = ws + o;
    o = (o + bytes + 255) & ~(size_t)255;
    return r;
  };
  // ---- zero-init zone (single custom zero kernel) ----
  char* zbase = ws;
  int* deg = (int*)alloc((size_t)N * 4);
  float* Uacc = (float*)alloc((size_t)G * F * 4);
  float* valg = (float*)alloc((size_t)G * 4);
  float* cntg = (float*)alloc((size_t)G * 4);
  size_t zbytes = o;  // multiple of 256
  // ---- rest ----
  int* off = (int*)alloc((size_t)(N + 1) * 4);
  int* cur = (int*)alloc((size_t)N * 4);
  float* dinv = (float*)alloc((size_t)N * 4);
  int* csr = (int*)alloc((size_t)E * 4);
  float* valn = (float*)alloc((size_t)N * 4);
  int* bsum = (int*)alloc(1024 * 4);
  float* bufA = (float*)alloc((size_t)N * F * 4);  // xs1, then h2
  float* bufB = (float*)alloc((size_t)N * F * 4);  // xs2 (=dinv*h1), then u
  (void)ws_size; (void)n_in;

  const int bs = 256;
  // custom zero (rocclr fillBuffer costs ~43us/dispatch regardless of size)
  int zn4 = (int)(zbytes / 16);
  k_zero<<<(zn4 + bs - 1) / bs, bs, 0, stream>>>((float4*)zbase, zn4);

  k_count_deg<<<2048, bs, 0, stream>>>(edst, deg, E, N);
  k_bsum<<<NB, bs, 0, stream>>>(deg, bsum, N);
  k_scan_bsum<<<1, 1024, 0, stream>>>(bsum, NB);
  k_scan_fin<<<NB, bs, 0, stream>>>(deg, bsum, off, cur, dinv, N);
  k_fill<<<2048, bs, 0, stream>>>(esrc, edst, cur, csr, E, N);

  // xs1 = dinv * x
  k_scale<<<2048, bs, 0, stream>>>(x, dinv, bufA, N);

  // 16 nodes per block (4 waves x 4 groups): exact single-pass grid
  int gBlocks = (N + 15) / 16;
  // layer 1: gather xs1, GEMV W_in, write dinv*h1 (= xs2) into bufB
  k_gcn<true><<<gBlocks, bs, 0, stream>>>(bufA, csr, off, dinv, W_in, b_in, bufB, N);
  // layer 2: gather xs2, GEMV W1, write raw h2 into bufA
  k_gcn<false><<<gBlocks, bs, 0, stream>>>(bufB, csr, off, dinv, W1, b1, bufA, N);

  // fused conv_val (MFConv) + conv_policy aggregation (single gather of h2 rows)
  k_mfpol<<<gBlocks, bs, 0, stream>>>(bufA, csr, off, dinv, Wl, bl, Wr, valn, bufB, N);

  int poolBlocks = (N + 255) / 256;
  k_pool2<<<poolBlocks, bs, 0, stream>>>(bufB, valn, batch, Uacc, valg, cntg, N);
  k_polfin<<<(G * P + bs - 1) / bs, bs, 0, stream>>>(Uacc, valg, cntg, W_pol, b_pol, out, G);
}

// Round 10
// 212.103 us; speedup vs baseline: 1.7676x; 1.1098x over previous
//
#include <hip/hip_runtime.h>

#define F 64
#define P 32
#define MAXD 10
#define NGRP 8  // dst-range groups, mapped to XCDs via blockIdx&7 (perf hint only)

// ---- bf16 helpers (RTN pack; unpack via shift/mask) ----
__device__ __forceinline__ unsigned short f2bf(float f) {
  unsigned b = __float_as_uint(f);
  return (unsigned short)((b + 0x7FFFu + ((b >> 16) & 1u)) >> 16);
}
__device__ __forceinline__ unsigned pk2(float a, float b) {
  return (unsigned)f2bf(a) | ((unsigned)f2bf(b) << 16);
}
__device__ __forceinline__ float blo(unsigned u) { return __uint_as_float(u << 16); }
__device__ __forceinline__ float bhi(unsigned u) { return __uint_as_float(u & 0xFFFF0000u); }

// ---------------- zero-init ----------------
__global__ void k_zero(float4* __restrict__ p, int n4) {
  int i = blockIdx.x * blockDim.x + threadIdx.x;
  int stride = gridDim.x * blockDim.x;
  float4 z = make_float4(0.f, 0.f, 0.f, 0.f);
  for (int idx = i; idx < n4; idx += stride) p[idx] = z;
}

// ---------------- degree count, XCD-partitioned by dst range ----------------
__global__ void k_count_deg(const int* __restrict__ dst, int* __restrict__ deg, int E, int N) {
  int r = blockIdx.x & (NGRP - 1);
  float scale = (float)NGRP / (float)N;
  int gblk = blockIdx.x >> 3;
  int i = gblk * blockDim.x + threadIdx.x;
  int stride = (gridDim.x >> 3) * blockDim.x;
  int E4 = E >> 2;
  const int4* d4p = (const int4*)dst;
  for (int e4 = i; e4 < E4; e4 += stride) {
    int4 d4 = d4p[e4];
    int rr;
    rr = min(NGRP - 1, (int)((float)d4.x * scale)); if (rr == r) atomicAdd(&deg[d4.x], 1);
    rr = min(NGRP - 1, (int)((float)d4.y * scale)); if (rr == r) atomicAdd(&deg[d4.y], 1);
    rr = min(NGRP - 1, (int)((float)d4.z * scale)); if (rr == r) atomicAdd(&deg[d4.z], 1);
    rr = min(NGRP - 1, (int)((float)d4.w * scale)); if (rr == r) atomicAdd(&deg[d4.w], 1);
  }
  for (int e = (E & ~3) + i; e < E; e += stride) {
    int d = dst[e];
    int rr = min(NGRP - 1, (int)((float)d * scale));
    if (rr == r) atomicAdd(&deg[d], 1);
  }
}

// ---------------- hierarchical scan ----------------
__global__ void k_bsum(const int* __restrict__ deg, int* __restrict__ bsum, int N) {
  __shared__ int s[256];
  int t = threadIdx.x;
  int n = blockIdx.x * 256 + t;
  s[t] = (n < N) ? deg[n] : 0;
  __syncthreads();
  for (int o = 128; o > 0; o >>= 1) {
    if (t < o) s[t] += s[t + o];
    __syncthreads();
  }
  if (t == 0) bsum[blockIdx.x] = s[0];
}

__global__ void k_scan_bsum(int* __restrict__ bsum, int B) {
  __shared__ int s[1024];
  int t = threadIdx.x;
  int v = (t < B) ? bsum[t] : 0;
  s[t] = v;
  __syncthreads();
  for (int o = 1; o < 1024; o <<= 1) {
    int u = (t >= o) ? s[t - o] : 0;
    __syncthreads();
    s[t] += u;
    __syncthreads();
  }
  if (t < B) bsum[t] = s[t] - v;
}

__global__ void k_scan_fin(const int* __restrict__ deg, const int* __restrict__ bsum,
                           int* __restrict__ off, int* __restrict__ cur,
                           float* __restrict__ dinv, int N) {
  __shared__ int s[256];
  int t = threadIdx.x;
  int n = blockIdx.x * 256 + t;
  int v = (n < N) ? deg[n] : 0;
  s[t] = v;
  __syncthreads();
  for (int o = 1; o < 256; o <<= 1) {
    int u = (t >= o) ? s[t - o] : 0;
    __syncthreads();
    s[t] += u;
    __syncthreads();
  }
  if (n < N) {
    int ex = bsum[blockIdx.x] + s[t] - v;
    off[n] = ex;
    cur[n] = ex;
    dinv[n] = rsqrtf((float)(v + 1));
    if (n == N - 1) off[N] = ex + v;
  }
}

// ---------------- CSR fill, XCD-partitioned ----------------
__global__ void k_fill(const int* __restrict__ src, const int* __restrict__ dst,
                       int* __restrict__ cur, int* __restrict__ csr, int E, int N) {
  int r = blockIdx.x & (NGRP - 1);
  float scale = (float)NGRP / (float)N;
  int gblk = blockIdx.x >> 3;
  int i = gblk * blockDim.x + threadIdx.x;
  int stride = (gridDim.x >> 3) * blockDim.x;
  int E4 = E >> 2;
  const int4* d4p = (const int4*)dst;
  for (int e4 = i; e4 < E4; e4 += stride) {
    int4 d4 = d4p[e4];
    int e = e4 * 4;
    int rr;
    rr = min(NGRP - 1, (int)((float)d4.x * scale));
    if (rr == r) { int pos = atomicAdd(&cur[d4.x], 1); csr[pos] = src[e]; }
    rr = min(NGRP - 1, (int)((float)d4.y * scale));
    if (rr == r) { int pos = atomicAdd(&cur[d4.y], 1); csr[pos] = src[e + 1]; }
    rr = min(NGRP - 1, (int)((float)d4.z * scale));
    if (rr == r) { int pos = atomicAdd(&cur[d4.z], 1); csr[pos] = src[e + 2]; }
    rr = min(NGRP - 1, (int)((float)d4.w * scale));
    if (rr == r) { int pos = atomicAdd(&cur[d4.w], 1); csr[pos] = src[e + 3]; }
  }
  for (int e = (E & ~3) + i; e < E; e += stride) {
    int d = dst[e];
    int rr = min(NGRP - 1, (int)((float)d * scale));
    if (rr == r) { int pos = atomicAdd(&cur[d], 1); csr[pos] = src[e]; }
  }
}

// ---------------- xs16 = bf16(dinv[n] * x[n]) ----------------
__global__ void k_scale16(const float* __restrict__ x, const float* __restrict__ dinv,
                          uint2* __restrict__ xs, int N) {
  int i = blockIdx.x * blockDim.x + threadIdx.x;
  int stride = gridDim.x * blockDim.x;
  int tot = N * (F / 4);
  const float4* x4 = (const float4*)x;
  for (int idx = i; idx < tot; idx += stride) {
    int n = idx >> 4;
    float d = dinv[n];
    float4 v = x4[idx];
    uint2 p;
    p.x = pk2(v.x * d, v.y * d);
    p.y = pk2(v.z * d, v.w * d);
    xs[idx] = p;
  }
}

// readlane: compile-time source lane (after unroll)
__device__ __forceinline__ float rdlane(float v, int srclane) {
  return __int_as_float(__builtin_amdgcn_readlane(__float_as_int(v), srclane));
}

__device__ __forceinline__ void addbf(float4& a, uint2 p) {
  a.x += blo(p.x); a.y += bhi(p.x); a.z += blo(p.y); a.w += bhi(p.y);
}

// ---------------- fused GCN layer: bf16 gather + fp32 GEMV, node-per-group ----------------
// rows: 32 u32 per node (64 bf16). lane l (of 16) covers feats 4l..4l+3 = (lo,hi,lo,hi).
template <bool WRITE_SCALED>
__global__ void k_gcn(const unsigned* __restrict__ xs, const int* __restrict__ csr,
                      const int* __restrict__ off, const float* __restrict__ dinv,
                      const float* __restrict__ W, const float* __restrict__ bias,
                      unsigned short* __restrict__ out, int N) {
  int wid = (blockIdx.x * blockDim.x + threadIdx.x) >> 6;
  int lane = threadIdx.x & 63;
  int nwaves = (gridDim.x * blockDim.x) >> 6;
  int g = lane >> 4, l = lane & 15;
  float w[F];
#pragma unroll
  for (int k = 0; k < F; ++k) w[k] = W[k * F + lane];  // W column `lane`
  float bv = bias[lane];
  for (int base = wid * 4; base < N; base += nwaves * 4) {
    int n = min(base + g, N - 1);
    int e0 = off[n], e1 = off[n + 1];
    float dnode = dinv[n];
    float4 acc = make_float4(0.f, 0.f, 0.f, 0.f);
    addbf(acc, *(const uint2*)&xs[(size_t)n * 32 + l * 2]);  // self term
    for (int win = e0; win < e1; win += 16) {
      int m = min(16, e1 - win);
      int ce = (win + l < e1) ? csr[win + l] : 0;  // 16 contiguous edges, coalesced
      int j = 0;
      for (; j + 4 <= m; j += 4) {  // 4 rows in flight per group (16/wave)
        int s0 = __shfl(ce, g * 16 + j + 0, 64);
        int s1 = __shfl(ce, g * 16 + j + 1, 64);
        int s2 = __shfl(ce, g * 16 + j + 2, 64);
        int s3 = __shfl(ce, g * 16 + j + 3, 64);
        uint2 q0 = *(const uint2*)&xs[(size_t)s0 * 32 + l * 2];
        uint2 q1 = *(const uint2*)&xs[(size_t)s1 * 32 + l * 2];
        uint2 q2 = *(const uint2*)&xs[(size_t)s2 * 32 + l * 2];
        uint2 q3 = *(const uint2*)&xs[(size_t)s3 * 32 + l * 2];
        addbf(acc, q0); addbf(acc, q1); addbf(acc, q2); addbf(acc, q3);
      }
      for (; j < m; ++j) {
        int s = __shfl(ce, g * 16 + j, 64);
        addbf(acc, *(const uint2*)&xs[(size_t)s * 32 + l * 2]);
      }
    }
    // GEMV per node (gg compile-time after unroll -> readlane legal)
#pragma unroll
    for (int gg = 0; gg < 4; ++gg) {
      float y0 = 0.f, y1 = 0.f, y2 = 0.f, y3 = 0.f;
#pragma unroll
      for (int k = 0; k < F; k += 4) {
        y0 += rdlane(acc.x, gg * 16 + (k >> 2)) * w[k + 0];
        y1 += rdlane(acc.y, gg * 16 + (k >> 2)) * w[k + 1];
        y2 += rdlane(acc.z, gg * 16 + (k >> 2)) * w[k + 2];
        y3 += rdlane(acc.w, gg * 16 + (k >> 2)) * w[k + 3];
      }
      float dd = rdlane(dnode, gg * 16);
      float y = dd * ((y0 + y1) + (y2 + y3)) + bv;
      if (WRITE_SCALED) y *= dd;
      int nn = base + gg;
      if (nn < N) out[(size_t)nn * F + lane] = f2bf(y);
    }
  }
}

// ---------------- fused MFConv + policy aggregation, bf16 gather ----------------
__global__ void k_mfpol(const unsigned* __restrict__ H, const int* __restrict__ csr,
                        const int* __restrict__ off, const float* __restrict__ dinv,
                        const float* __restrict__ Wl, const float* __restrict__ bl,
                        const float* __restrict__ Wr, float* __restrict__ val,
                        float* __restrict__ u, int N) {
  int wid = (blockIdx.x * blockDim.x + threadIdx.x) >> 6;
  int lane = threadIdx.x & 63;
  int nwaves = (gridDim.x * blockDim.x) >> 6;
  int g = lane >> 4, l = lane & 15;
  for (int base = wid * 4; base < N; base += nwaves * 4) {
    bool valid = (base + g) < N;
    int n = min(base + g, N - 1);
    int e0 = off[n], e1 = off[n + 1];
    float dn = dinv[n];
    float4 ah = make_float4(0.f, 0.f, 0.f, 0.f);
    float4 aw = make_float4(0.f, 0.f, 0.f, 0.f);
    for (int win = e0; win < e1; win += 16) {
      int m = min(16, e1 - win);
      bool p = (win + l < e1);
      int ce = p ? csr[win + l] : 0;
      float cd = p ? dinv[ce] : 0.f;
      int j = 0;
      for (; j + 4 <= m; j += 4) {
        int s0 = __shfl(ce, g * 16 + j + 0, 64);
        int s1 = __shfl(ce, g * 16 + j + 1, 64);
        int s2 = __shfl(ce, g * 16 + j + 2, 64);
        int s3 = __shfl(ce, g * 16 + j + 3, 64);
        float d0 = __shfl(cd, g * 16 + j + 0, 64);
        float d1 = __shfl(cd, g * 16 + j + 1, 64);
        float d2 = __shfl(cd, g * 16 + j + 2, 64);
        float d3 = __shfl(cd, g * 16 + j + 3, 64);
        uint2 q0 = *(const uint2*)&H[(size_t)s0 * 32 + l * 2];
        uint2 q1 = *(const uint2*)&H[(size_t)s1 * 32 + l * 2];
        uint2 q2 = *(const uint2*)&H[(size_t)s2 * 32 + l * 2];
        uint2 q3 = *(const uint2*)&H[(size_t)s3 * 32 + l * 2];
        float f0x = blo(q0.x), f0y = bhi(q0.x), f0z = blo(q0.y), f0w = bhi(q0.y);
        float f1x = blo(q1.x), f1y = bhi(q1.x), f1z = blo(q1.y), f1w = bhi(q1.y);
        float f2x = blo(q2.x), f2y = bhi(q2.x), f2z = blo(q2.y), f2w = bhi(q2.y);
        float f3x = blo(q3.x), f3y = bhi(q3.x), f3z = blo(q3.y), f3w = bhi(q3.y);
        ah.x += (f0x + f1x) + (f2x + f3x);
        ah.y += (f0y + f1y) + (f2y + f3y);
        ah.z += (f0z + f1z) + (f2z + f3z);
        ah.w += (f0w + f1w) + (f2w + f3w);
        aw.x += (d0 * f0x + d1 * f1x) + (d2 * f2x + d3 * f3x);
        aw.y += (d0 * f0y + d1 * f1y) + (d2 * f2y + d3 * f3y);
        aw.z += (d0 * f0z + d1 * f1z) + (d2 * f2z + d3 * f3z);
        aw.w += (d0 * f0w + d1 * f1w) + (d2 * f2w + d3 * f3w);
      }
      for (; j < m; ++j) {
        int s = __shfl(ce, g * 16 + j, 64);
        float dd = __shfl(cd, g * 16 + j, 64);
        uint2 q = *(const uint2*)&H[(size_t)s * 32 + l * 2];
        float fx = blo(q.x), fy = bhi(q.x), fz = blo(q.y), fw = bhi(q.y);
        ah.x += fx; ah.y += fy; ah.z += fz; ah.w += fw;
        aw.x += dd * fx; aw.y += dd * fy; aw.z += dd * fz; aw.w += dd * fw;
      }
    }
    int dc = min(e1 - e0, MAXD);
    uint2 qn = *(const uint2*)&H[(size_t)n * 32 + l * 2];
    float4 hn = make_float4(blo(qn.x), bhi(qn.x), blo(qn.y), bhi(qn.y));
    float4 wl4 = *(const float4*)&Wl[dc * F + l * 4];
    float4 wr4 = *(const float4*)&Wr[dc * F + l * 4];
    float part = ah.x * wl4.x + ah.y * wl4.y + ah.z * wl4.z + ah.w * wl4.w
               + hn.x * wr4.x + hn.y * wr4.y + hn.z * wr4.z + hn.w * wr4.w;
#pragma unroll
    for (int o = 1; o < 16; o <<= 1) part += __shfl_xor(part, o, 64);  // in-group reduce
    if (l == 0 && valid) val[n] = part + bl[dc];
    if (valid) {
      float4 r;
      r.x = (aw.x + dn * hn.x) * dn;
      r.y = (aw.y + dn * hn.y) * dn;
      r.z = (aw.z + dn * hn.z) * dn;
      r.w = (aw.w + dn * hn.w) * dn;
      *(float4*)&u[(size_t)n * F + l * 4] = r;
    }
  }
}

// ---------------- pooling (batch sorted) ----------------
__global__ void k_pool2(const float* __restrict__ u, const float* __restrict__ valn,
                        const int* __restrict__ batch, float* __restrict__ Uacc,
                        float* __restrict__ valg, float* __restrict__ cntg, int N) {
  __shared__ float Ul[64 * F];
  __shared__ float Vl[64], Cl[64];
  int t = threadIdx.x;
  for (int i = t; i < 64 * F; i += 256) Ul[i] = 0.f;
  if (t < 64) { Vl[t] = 0.f; Cl[t] = 0.f; }
  __syncthreads();
  int base = blockIdx.x * 256;
  int f = t & 63, r = t >> 6;
  for (int i = r; i < 256; i += 4) {
    int n = base + i;
    if (n >= N) break;
    int g = batch[n];
    atomicAdd(&Ul[g * F + f], u[(size_t)n * F + f]);
    if (f == 0) { atomicAdd(&Vl[g], valn[n]); atomicAdd(&Cl[g], 1.f); }
  }
  __syncthreads();
  int last = min(base + 256, N) - 1;
  if (last < base) return;
  int gmin = batch[base], gmax = batch[last];
  int ng = gmax - gmin + 1;
  for (int idx = t; idx < ng * F; idx += 256) {
    int g = gmin + (idx >> 6), ff = idx & 63;
    atomicAdd(&Uacc[g * F + ff], Ul[g * F + ff]);
  }
  for (int idx = t; idx < ng; idx += 256) {
    int g = gmin + idx;
    atomicAdd(&valg[g], Vl[g]);
    atomicAdd(&cntg[g], Cl[g]);
  }
}

// ---------------- finalize ----------------
__global__ void k_polfin(const float* __restrict__ Uacc, const float* __restrict__ valg,
                         const float* __restrict__ cntg, const float* __restrict__ W_pol,
                         const float* __restrict__ b_pol, float* __restrict__ out, int G) {
  int i = blockIdx.x * blockDim.x + threadIdx.x;
  if (i < G * P) {
    int g = i >> 5, p = i & 31;
    float s = 0.f;
#pragma unroll
    for (int k = 0; k < F; ++k) s += Uacc[g * F + k] * W_pol[k * P + p];
    out[i] = s / fmaxf(cntg[g], 1.f) + b_pol[p];
  }
  if (i < G) out[(size_t)G * P + i] = valg[i];
}

extern "C" void kernel_launch(void* const* d_in, const int* in_sizes, int n_in,
                              void* d_out, int out_size, void* d_ws, size_t ws_size,
                              hipStream_t stream) {
  const float* x = (const float*)d_in[0];
  const int* ei = (const int*)d_in[1];
  const int* batch = (const int*)d_in[2];
  const float* W_in = (const float*)d_in[3];
  const float* b_in = (const float*)d_in[4];
  const float* W1 = (const float*)d_in[5];
  const float* b1 = (const float*)d_in[6];
  const float* Wl = (const float*)d_in[7];
  const float* bl = (const float*)d_in[8];
  const float* Wr = (const float*)d_in[9];
  const float* W_pol = (const float*)d_in[10];
  const float* b_pol = (const float*)d_in[11];
  float* out = (float*)d_out;

  const int N = in_sizes[0] / F;
  const int E = in_sizes[1] / 2;
  const int G = out_size / (P + 1);
  const int* esrc = ei;
  const int* edst = ei + E;
  const int NB = (N + 255) / 256;

  char* ws = (char*)d_ws;
  size_t o = 0;
  auto alloc = [&](size_t bytes) {
    char* r = ws + o;
    o = (o + bytes + 255) & ~(size_t)255;
    return r;
  };
  // ---- zero-init zone ----
  char* zbase = ws;
  int* deg = (int*)alloc((size_t)N * 4);
  float* Uacc = (float*)alloc((size_t)G * F * 4);
  float* valg = (float*)alloc((size_t)G * 4);
  float* cntg = (float*)alloc((size_t)G * 4);
  size_t zbytes = o;  // multiple of 256
  // ---- rest ----
  int* off = (int*)alloc((size_t)(N + 1) * 4);
  int* cur = (int*)alloc((size_t)N * 4);
  float* dinv = (float*)alloc((size_t)N * 4);
  int* csr = (int*)alloc((size_t)E * 4);
  float* valn = (float*)alloc((size_t)N * 4);
  int* bsum = (int*)alloc(1024 * 4);
  unsigned* xs16 = (unsigned*)alloc((size_t)N * F * 2);  // bf16 x*dinv
  unsigned* t16 = (unsigned*)alloc((size_t)N * F * 2);   // bf16 dinv*h1
  unsigned* h16 = (unsigned*)alloc((size_t)N * F * 2);   // bf16 h2
  float* u = (float*)alloc((size_t)N * F * 4);           // fp32 policy-agg
  (void)ws_size; (void)n_in;

  const int bs = 256;
  int zn4 = (int)(zbytes / 16);
  k_zero<<<(zn4 + bs - 1) / bs, bs, 0, stream>>>((float4*)zbase, zn4);

  k_count_deg<<<2048, bs, 0, stream>>>(edst, deg, E, N);
  k_bsum<<<NB, bs, 0, stream>>>(deg, bsum, N);
  k_scan_bsum<<<1, 1024, 0, stream>>>(bsum, NB);
  k_scan_fin<<<NB, bs, 0, stream>>>(deg, bsum, off, cur, dinv, N);
  k_fill<<<2048, bs, 0, stream>>>(esrc, edst, cur, csr, E, N);

  // xs16 = bf16(dinv * x)
  k_scale16<<<2048, bs, 0, stream>>>(x, dinv, (uint2*)xs16, N);

  // 16 nodes per block (4 waves x 4 groups)
  int gBlocks = (N + 15) / 16;
  k_gcn<true><<<gBlocks, bs, 0, stream>>>(xs16, csr, off, dinv, W_in, b_in,
                                          (unsigned short*)t16, N);
  k_gcn<false><<<gBlocks, bs, 0, stream>>>(t16, csr, off, dinv, W1, b1,
                                           (unsigned short*)h16, N);
  k_mfpol<<<gBlocks, bs, 0, stream>>>(h16, csr, off, dinv, Wl, bl, Wr, valn, u, N);

  int poolBlocks = (N + 255) / 256;
  k_pool2<<<poolBlocks, bs, 0, stream>>>(u, valn, batch, Uacc, valg, cntg, N);
  k_polfin<<<(G * P + bs - 1) / bs, bs, 0, stream>>>(Uacc, valg, cntg, W_pol, b_pol, out, G);
}